// Round 14
// baseline (882.992 us; speedup 1.0000x reference)
//
#include <hip/hip_runtime.h>

#define NB 2
#define NQ 4096
#define NPTS 8192
#define KNN 32
#define CF 128
#define MPOS (NB*NQ*KNN)
#define EPSV 1e-5f

typedef __attribute__((ext_vector_type(8))) short bf16x8;
typedef __attribute__((ext_vector_type(4))) float f32x4;
typedef __attribute__((ext_vector_type(4))) unsigned int u32x4;
typedef unsigned long long u64;

__device__ __forceinline__ unsigned short f2b(float f){
  unsigned u = __float_as_uint(f);
  return (unsigned short)((u + 0x7fffu + ((u >> 16) & 1u)) >> 16);
}
__device__ __forceinline__ float b2f(unsigned short h){
  return __uint_as_float(((unsigned)h) << 16);
}
// XOR swizzle for LDS tiles with 256B rows (bf16[128] rows).
__device__ __forceinline__ unsigned swz(unsigned byte){
  return byte ^ (((byte >> 8) & 7u) << 4);
}

// ---------------- prep: points SoA + weights to bf16 hi/lo (fused) ----------
__global__ void k_prep(const float* __restrict__ p1, const float* __restrict__ p2,
                       const float* __restrict__ aw1, const float* __restrict__ bw1,
                       const float* __restrict__ aw2, const float* __restrict__ bw2,
                       float* __restrict__ px, float* __restrict__ py, float* __restrict__ pz,
                       unsigned short* __restrict__ w1h, unsigned short* __restrict__ w1l,
                       unsigned short* __restrict__ w2h, unsigned short* __restrict__ w2l){
  int t = blockIdx.x*256 + threadIdx.x;
  if (t < NB*NPTS){
    int b = t / NPTS, p = t - b*NPTS;
    const float* s = (p < NQ) ? p1 : p2;
    int pp = (p < NQ) ? p : p - NQ;
    px[t] = s[(b*3+0)*NQ + pp];
    py[t] = s[(b*3+1)*NQ + pp];
    pz[t] = s[(b*3+2)*NQ + pp];
  } else {
    int u = t - NB*NPTS;
    if (u < 32768){
      float w = u < 16384 ? aw1[u] : bw1[u-16384];
      unsigned short hi = f2b(w);
      w1h[u] = hi; w1l[u] = f2b(w - b2f(hi));
    } else {
      int v = u - 32768;
      if (v < 65536){
        float w = v < 32768 ? aw2[v] : bw2[v-32768];
        unsigned short hi = f2b(w);
        w2h[v] = hi; w2l[v] = f2b(w - b2f(hi));
      }
    }
  }
}

// ---------------- prep: feature transpose to [b][p][c] f32 ----------------
__global__ void k_transpose_f(const float* __restrict__ f1, const float* __restrict__ f2,
                              float* __restrict__ fT){
  __shared__ float tile[32][33];
  int p0 = blockIdx.x*32, c0 = blockIdx.y*32, b = blockIdx.z;
  const float* s = (p0 < NQ) ? f1 : f2;
  int pp0 = (p0 < NQ) ? p0 : p0 - NQ;
  int tx = threadIdx.x & 31, ty = threadIdx.x >> 5;
  #pragma unroll
  for (int i = 0; i < 32; i += 8)
    tile[ty+i][tx] = s[((size_t)b*CF + c0+ty+i)*NQ + pp0 + tx];
  __syncthreads();
  #pragma unroll
  for (int i = 0; i < 32; i += 8)
    fT[((size_t)b*NPTS + p0+ty+i)*CF + c0 + tx] = tile[tx][ty+i];
}

// ---------------- KNN: one wave per query, 16 waves/block ----------------
// Replicates the reference d2 formula in strict f32 (no FMA).
__global__ __launch_bounds__(1024,1) void k_knn(const float* __restrict__ gpx, const float* __restrict__ gpy,
        const float* __restrict__ gpz, const int* __restrict__ randidx,
        int* __restrict__ nn_idx, float* __restrict__ newf){
  __shared__ float4 sp[NPTS];
  __shared__ u64 sbuf[16][192];
  const int b = blockIdx.y;
  for (int i = threadIdx.x; i < NPTS; i += 1024){
    float x = gpx[b*NPTS+i], y = gpy[b*NPTS+i], z = gpz[b*NPTS+i];
    float sq = __fadd_rn(__fadd_rn(__fmul_rn(x,x), __fmul_rn(y,y)), __fmul_rn(z,z));
    sp[i] = make_float4(x, y, z, sq);
  }
  __syncthreads();
  const int wv = threadIdx.x >> 6, lane = threadIdx.x & 63;
  const int m = blockIdx.x*16 + wv;
  const int ridx = randidx[m];
  const float4 Q = sp[ridx];
  const float qx = Q.x, qy = Q.y, qz = Q.z, s1q = Q.w;
  u64* buf = sbuf[wv];

  u64 top = ~0ull;
  float thr = __builtin_inff();
  int cnt = 0;

  auto flush = [&](){
    u64 e0 = (lane       < cnt) ? buf[lane]     : ~0ull;
    u64 e1 = (lane + 64  < cnt) ? buf[lane+64]  : ~0ull;
    u64 e2 = (lane + 128 < cnt) ? buf[lane+128] : ~0ull;
    u64 e3 = (lane < KNN) ? top : ~0ull;
    #define SWP(a,b) { u64 lo_ = (a<b)?a:b; u64 hi_ = (a<b)?b:a; a=lo_; b=hi_; }
    SWP(e0,e1) SWP(e2,e3) SWP(e0,e2) SWP(e1,e3) SWP(e1,e2)
    #undef SWP
    u64 newtop = ~0ull, v = 0;
    for (int i = 0; i < KNN; ++i){
      v = e0;
      #pragma unroll
      for (int s = 1; s < 64; s <<= 1){
        u64 o = __shfl_xor(v, s);
        if (o < v) v = o;
      }
      bool win = (e0 == v);
      e0 = win ? e1 : e0; e1 = win ? e2 : e1; e2 = win ? e3 : e2;
      e3 = win ? ~0ull : e3;
      newtop = (lane == i) ? v : newtop;
    }
    top = newtop;
    unsigned k32 = (unsigned)(v >> 32);
    unsigned uu = (k32 & 0x80000000u) ? (k32 ^ 0x80000000u) : ~k32;
    thr = __uint_as_float(uu);
    cnt = 0;
  };

  for (int c = 0; c < NPTS/64; ++c){
    if (cnt > 128) flush();
    int j = c*64 + lane;
    float4 P = sp[j];
    float dot = __fadd_rn(__fadd_rn(__fmul_rn(qx,P.x), __fmul_rn(qy,P.y)), __fmul_rn(qz,P.z));
    float d   = __fsub_rn(__fadd_rn(s1q, P.w), __fmul_rn(2.0f, dot));
    bool pred = (d <= thr);
    u64 mask = __ballot(pred);
    if (mask){
      if (pred){
        int rank = __popcll(mask & ((1ull << lane) - 1ull));
        unsigned u = __float_as_uint(d);
        unsigned key = u ^ ((unsigned)((int)u >> 31) | 0x80000000u);
        buf[cnt + rank] = ((u64)key << 32) | (unsigned)j;
      }
      cnt += __popcll(mask);
    }
  }
  flush();

  if (lane < KNN){
    int idx = (int)(unsigned)(top & 0xffffffffull);
    size_t pos = (size_t)(b*NQ + m)*KNN + lane;
    nn_idx[pos] = idx;
    float4 P = sp[idx];
    float rx = P.x-qx, ry = P.y-qy, rz = P.z-qz;
    float dd = sqrtf(rx*rx + ry*ry + rz*rz);
    float* nf = newf + pos*5;
    nf[0] = rx; nf[1] = ry; nf[2] = rz; nf[3] = dd;
  }
}

// ---------------- fdot channel: lane=(k,half), 64 ch per lane ----------------
__global__ void k_fdot(const float* __restrict__ fT, const int* __restrict__ randidx,
                       const int* __restrict__ nn_idx, float* __restrict__ newf){
  const int wv = threadIdx.x >> 6, lane = threadIdx.x & 63;
  const int m = blockIdx.x*4 + wv, b = blockIdx.y;
  const int k = lane >> 1, half = lane & 1;
  const int ridx = randidx[m];
  const int idx = nn_idx[(size_t)(b*NQ + m)*KNN + k];
  const float* f1p = fT + ((size_t)b*NPTS + ridx)*CF + half*64;
  const float* gp  = fT + ((size_t)b*NPTS + idx )*CF + half*64;
  float s = 0.0f;
  #pragma unroll
  for (int c = 0; c < 16; ++c){
    float4 a = *(const float4*)(f1p + c*4);
    float4 g = *(const float4*)(gp  + c*4);
    s += a.x*g.x + a.y*g.y + a.z*g.z + a.w*g.w;
  }
  s += __shfl_xor(s, 1);
  if (half == 0)
    newf[((size_t)(b*NQ + m)*KNN + k)*5 + 4] = s;
}

// ---------------- moments of newf (for analytic y0 stats) ----------------
__global__ void k_moments(const float* __restrict__ newf, float* __restrict__ mom){
  float v[20];
  #pragma unroll
  for (int i = 0; i < 20; ++i) v[i] = 0.0f;
  int p = blockIdx.x*256 + threadIdx.x;
  if (p < MPOS){
    const float* nf = newf + (size_t)p*5;
    float x0=nf[0], x1=nf[1], x2=nf[2], x3=nf[3], x4=nf[4];
    v[0]=x0; v[1]=x1; v[2]=x2; v[3]=x3; v[4]=x4;
    v[5]=x0*x0; v[6]=x0*x1; v[7]=x0*x2; v[8]=x0*x3; v[9]=x0*x4;
    v[10]=x1*x1; v[11]=x1*x2; v[12]=x1*x3; v[13]=x1*x4;
    v[14]=x2*x2; v[15]=x2*x3; v[16]=x2*x4;
    v[17]=x3*x3; v[18]=x3*x4; v[19]=x4*x4;
  }
  #pragma unroll
  for (int i = 0; i < 20; ++i){
    float t = v[i];
    #pragma unroll
    for (int sh = 1; sh < 64; sh <<= 1) t += __shfl_xor(t, sh);
    v[i] = t;
  }
  __shared__ float red[4][20];
  int wv = threadIdx.x >> 6, lane = threadIdx.x & 63;
  if (lane == 0){
    #pragma unroll
    for (int i = 0; i < 20; ++i) red[wv][i] = v[i];
  }
  __syncthreads();
  if (threadIdx.x < 20)
    atomicAdd(&mom[threadIdx.x],
              red[0][threadIdx.x]+red[1][threadIdx.x]+red[2][threadIdx.x]+red[3][threadIdx.x]);
}

// ---------------- stat passes: 256-thread blocks, BM=128 ----------------
// PASS 1: L0+L1, accumulate y1 sum/sumsq.  PASS 2: chain to y2, sum/sumsq.
// launch_bounds(256,3); L2 stat GEMM in FOUR 32-channel chunks (a2[4][2]).
// x2 writeback packs lane pairs into u32 ds_writes (conflict fix, bit-identical).
template<int PASS>
__global__ __launch_bounds__(256,3) void k_pass(
    const float* __restrict__ newf,
    const float* __restrict__ aw0, const float* __restrict__ bw0,
    const float* __restrict__ ag0, const float* __restrict__ bg0,
    const float* __restrict__ abe0, const float* __restrict__ bbe0,
    const float* __restrict__ ag1, const float* __restrict__ bg1,
    const float* __restrict__ abe1, const float* __restrict__ bbe1,
    const unsigned short* __restrict__ w1b, const unsigned short* __restrict__ w2b,
    const float* __restrict__ mom,
    float* __restrict__ y1s, float* __restrict__ y1q,
    float* __restrict__ y2s, float* __restrict__ y2q)
{
  __shared__ unsigned short sX[128*128];   // x1 then x2 tile, swizzled 256B rows
  __shared__ float sF0[128*5], sFb0[128];
  __shared__ float sA1[128], sB1[128];
  __shared__ float sStat[512];

  const int tid = threadIdx.x;
  const int br = blockIdx.y;
  const float invM = 1.0f / (float)MPOS;

  if (tid < 128){
    const float* w0 = (br ? bw0 : aw0) + tid*5;
    float g  = (br ? bg0 : ag0)[tid];
    float be = (br ? bbe0: abe0)[tid];
    float w[5], m5[5];
    #pragma unroll
    for (int i=0;i<5;++i){ w[i]=w0[i]; m5[i]=mom[i]*invM; }
    float mu = 0;
    #pragma unroll
    for (int i=0;i<5;++i) mu += w[i]*m5[i];
    const int I[15] = {0,0,0,0,0,1,1,1,1,2,2,2,3,3,4};
    const int J[15] = {0,1,2,3,4,1,2,3,4,2,3,4,3,4,4};
    float e2 = 0;
    #pragma unroll
    for (int t2=0;t2<15;++t2){
      float c = (I[t2]==J[t2]) ? 1.0f : 2.0f;
      e2 += c * w[I[t2]] * w[J[t2]] * (mom[5+t2]*invM);
    }
    float var = fmaxf(e2 - mu*mu, 0.0f);
    float A = g * rsqrtf(var + EPSV);
    #pragma unroll
    for (int i=0;i<5;++i) sF0[tid*5+i] = A*w[i];
    sFb0[tid] = be - A*mu;
  }
  if (PASS >= 2 && tid < 128){
    float s = y1s[br*128+tid]*invM, q = y1q[br*128+tid]*invM;
    float var = fmaxf(q - s*s, 0.0f);
    float g = (br ? bg1 : ag1)[tid], be = (br ? bbe1 : abe1)[tid];
    float A = g*rsqrtf(var + EPSV);
    sA1[tid] = A; sB1[tid] = be - A*s;
  }
  sStat[tid] = 0.0f; sStat[256+tid] = 0.0f;

  const int p = tid >> 1, h = tid & 1;
  const size_t gp = (size_t)blockIdx.x*128 + p;
  const float* nf = newf + gp*5;
  float x0 = nf[0], x1v = nf[1], x2v = nf[2], x3v = nf[3], x4v = nf[4];
  __syncthreads();
  #pragma unroll
  for (int cc = 0; cc < 8; ++cc){
    int oc = h*64 + cc*8;
    u32x4 vv;
    #pragma unroll
    for (int jj = 0; jj < 4; ++jj){
      int o = oc + jj*2;
      float ya = sFb0[o]   + sF0[o*5+0]*x0 + sF0[o*5+1]*x1v + sF0[o*5+2]*x2v + sF0[o*5+3]*x3v + sF0[o*5+4]*x4v;
      float yb = sFb0[o+1] + sF0[(o+1)*5+0]*x0 + sF0[(o+1)*5+1]*x1v + sF0[(o+1)*5+2]*x2v + sF0[(o+1)*5+3]*x3v + sF0[(o+1)*5+4]*x4v;
      vv[jj] = (unsigned)f2b(fmaxf(ya,0.0f)) | ((unsigned)f2b(fmaxf(yb,0.0f)) << 16);
    }
    *(u32x4*)((char*)sX + swz((unsigned)(p*256 + oc*2))) = vv;
  }
  __syncthreads();

  const int wv = tid >> 6, lane = tid & 63;
  const int mb = wv >> 1, nb = wv & 1;
  const int lrow = lane & 15, lk = lane >> 4;
  const unsigned short* w1g = w1b + br*16384;
  f32x4 zf = {0.0f, 0.0f, 0.0f, 0.0f};
  f32x4 acc[4][4];
  #pragma unroll
  for (int i=0;i<4;++i)
    #pragma unroll
    for (int j=0;j<4;++j) acc[i][j] = zf;

  #pragma unroll
  for (int ks = 0; ks < 4; ++ks){
    bf16x8 af[4], bfr[4];
    #pragma unroll
    for (int mf = 0; mf < 4; ++mf){
      int row = mb*64 + mf*16 + lrow;
      af[mf] = *(bf16x8*)((char*)sX + swz((unsigned)(row*256 + ks*64 + lk*16)));
    }
    #pragma unroll
    for (int nf2 = 0; nf2 < 4; ++nf2){
      int o = nb*64 + nf2*16 + lrow;
      bfr[nf2] = *(const bf16x8*)(w1g + o*128 + ks*32 + lk*8);
    }
    #pragma unroll
    for (int mf = 0; mf < 4; ++mf)
      #pragma unroll
      for (int nf2 = 0; nf2 < 4; ++nf2)
        acc[mf][nf2] = __builtin_amdgcn_mfma_f32_16x16x32_bf16(af[mf], bfr[nf2], acc[mf][nf2], 0, 0, 0);
  }

  if (PASS == 1){
    #pragma unroll
    for (int nf2 = 0; nf2 < 4; ++nf2){
      float s = 0, q = 0;
      #pragma unroll
      for (int mf=0;mf<4;++mf)
        #pragma unroll
        for (int r=0;r<4;++r){ float v2 = acc[mf][nf2][r]; s += v2; q += v2*v2; }
      s += __shfl_xor(s,16); s += __shfl_xor(s,32);
      q += __shfl_xor(q,16); q += __shfl_xor(q,32);
      if (lane < 16){
        int o = nb*64 + nf2*16 + lrow;
        atomicAdd(&sStat[o], s);
        atomicAdd(&sStat[256+o], q);
      }
    }
    __syncthreads();
    if (tid < 128){
      atomicAdd(&y1s[br*128 + tid], sStat[tid]);
      atomicAdd(&y1q[br*128 + tid], sStat[256+tid]);
    }
    return;
  }

  __syncthreads();   // all waves done reading sX(x1)
  // x2 = relu(bn1(y1)) -> sX; lane pairs (lrow even/odd) pack 2 channels
  // into one u32 ds_write (sub-word conflict fix; LDS bytes identical).
  #pragma unroll
  for (int nf2 = 0; nf2 < 4; ++nf2){
    int o = nb*64 + nf2*16 + lrow;
    float A = sA1[o], Bc = sB1[o];
    #pragma unroll
    for (int mf = 0; mf < 4; ++mf)
      #pragma unroll
      for (int r = 0; r < 4; ++r){
        float xv = fmaxf(fmaf(A, acc[mf][nf2][r], Bc), 0.0f);
        float xp = __shfl_xor(xv, 1);
        if (!(lrow & 1)){
          int mm = mb*64 + mf*16 + lk*4 + r;
          unsigned wd = (unsigned)f2b(xv) | ((unsigned)f2b(xp) << 16);
          *(unsigned*)((char*)sX + swz((unsigned)(mm*256 + o*2))) = wd;
        }
      }
  }
  __syncthreads();

  // L2 stat GEMM in FOUR 32-channel chunks (a2[4][2] keeps reg demand low)
  const unsigned short* w2 = w2b + br*32768;
  #pragma unroll
  for (int nh = 0; nh < 4; ++nh){
    f32x4 a2[4][2];
    #pragma unroll
    for (int i=0;i<4;++i)
      #pragma unroll
      for (int j=0;j<2;++j) a2[i][j] = zf;
    #pragma unroll
    for (int ks = 0; ks < 4; ++ks){
      bf16x8 af[4];
      #pragma unroll
      for (int mf = 0; mf < 4; ++mf){
        int row = mb*64 + mf*16 + lrow;
        af[mf] = *(bf16x8*)((char*)sX + swz((unsigned)(row*256 + ks*64 + lk*16)));
      }
      bf16x8 bw2f[2];
      #pragma unroll
      for (int nf2 = 0; nf2 < 2; ++nf2){
        int o = nb*128 + nh*32 + nf2*16 + lrow;
        bw2f[nf2] = *(const bf16x8*)(w2 + o*128 + ks*32 + lk*8);
      }
      #pragma unroll
      for (int mf = 0; mf < 4; ++mf)
        #pragma unroll
        for (int nf2 = 0; nf2 < 2; ++nf2)
          a2[mf][nf2] = __builtin_amdgcn_mfma_f32_16x16x32_bf16(af[mf], bw2f[nf2], a2[mf][nf2], 0, 0, 0);
    }
    #pragma unroll
    for (int nf2 = 0; nf2 < 2; ++nf2){
      float s = 0, q = 0;
      #pragma unroll
      for (int mf=0;mf<4;++mf)
        #pragma unroll
        for (int r=0;r<4;++r){ float v2 = a2[mf][nf2][r]; s += v2; q += v2*v2; }
      s += __shfl_xor(s,16); s += __shfl_xor(s,32);
      q += __shfl_xor(q,16); q += __shfl_xor(q,32);
      if (lane < 16){
        int o = nb*128 + nh*32 + nf2*16 + lrow;
        atomicAdd(&sStat[o], s);
        atomicAdd(&sStat[256+o], q);
      }
    }
  }
  __syncthreads();
  atomicAdd(&y2s[br*256 + tid], sStat[tid]);
  atomicAdd(&y2q[br*256 + tid], sStat[256+tid]);
}

// ---------------- final pass: split-bf16, 256-thread blocks, BM=64 ----------
// launch_bounds(256,3): verified optimum (R9/R11). (256,4) spills (R10).
// x2 writeback packs lane pairs into u32 ds_writes (conflict fix).
__global__ __launch_bounds__(256,3) void k_pass3(
    const float* __restrict__ newf,
    const float* __restrict__ aw0, const float* __restrict__ bw0,
    const float* __restrict__ ag0, const float* __restrict__ bg0,
    const float* __restrict__ abe0, const float* __restrict__ bbe0,
    const float* __restrict__ ag1, const float* __restrict__ bg1,
    const float* __restrict__ abe1, const float* __restrict__ bbe1,
    const float* __restrict__ ag2, const float* __restrict__ bg2,
    const float* __restrict__ abe2, const float* __restrict__ bbe2,
    const unsigned short* __restrict__ w1h, const unsigned short* __restrict__ w1l,
    const unsigned short* __restrict__ w2h, const unsigned short* __restrict__ w2l,
    const float* __restrict__ mom,
    const float* __restrict__ y1s, const float* __restrict__ y1q,
    const float* __restrict__ y2s, const float* __restrict__ y2q,
    float* __restrict__ tout)
{
  __shared__ unsigned short sXh[64*128], sXl[64*128];
  __shared__ float sF0[128*5], sFb0[128];
  __shared__ float sA1[128], sB1[128];
  __shared__ float sA2[256], sB2[256];
  __shared__ float sT[4][64];

  const int tid = threadIdx.x;
  const int br = blockIdx.y;
  const float invM = 1.0f / (float)MPOS;

  if (tid < 128){
    const float* w0 = (br ? bw0 : aw0) + tid*5;
    float g  = (br ? bg0 : ag0)[tid];
    float be = (br ? bbe0: abe0)[tid];
    float w[5], m5[5];
    #pragma unroll
    for (int i=0;i<5;++i){ w[i]=w0[i]; m5[i]=mom[i]*invM; }
    float mu = 0;
    #pragma unroll
    for (int i=0;i<5;++i) mu += w[i]*m5[i];
    const int I[15] = {0,0,0,0,0,1,1,1,1,2,2,2,3,3,4};
    const int J[15] = {0,1,2,3,4,1,2,3,4,2,3,4,3,4,4};
    float e2 = 0;
    #pragma unroll
    for (int t2=0;t2<15;++t2){
      float c = (I[t2]==J[t2]) ? 1.0f : 2.0f;
      e2 += c * w[I[t2]] * w[J[t2]] * (mom[5+t2]*invM);
    }
    float var = fmaxf(e2 - mu*mu, 0.0f);
    float A = g * rsqrtf(var + EPSV);
    #pragma unroll
    for (int i=0;i<5;++i) sF0[tid*5+i] = A*w[i];
    sFb0[tid] = be - A*mu;

    float s1 = y1s[br*128+tid]*invM, q1 = y1q[br*128+tid]*invM;
    float var1 = fmaxf(q1 - s1*s1, 0.0f);
    float g1 = (br ? bg1 : ag1)[tid], be1 = (br ? bbe1 : abe1)[tid];
    float A1 = g1*rsqrtf(var1 + EPSV);
    sA1[tid] = A1; sB1[tid] = be1 - A1*s1;
  }
  {
    int c2 = tid;           // 256 threads cover 256 channels
    float s = y2s[br*256+c2]*invM, q = y2q[br*256+c2]*invM;
    float var = fmaxf(q - s*s, 0.0f);
    float g = (br ? bg2 : ag2)[c2], be = (br ? bbe2 : abe2)[c2];
    float A = g*rsqrtf(var + EPSV);
    sA2[c2] = A; sB2[c2] = be - A*s;
  }

  // x1 tile: 4 threads per position, 32 channels each; split hi/lo
  const int p = tid >> 2, h = tid & 3;
  const size_t gp = (size_t)blockIdx.x*64 + p;
  const float* nf = newf + gp*5;
  float x0 = nf[0], x1v = nf[1], x2v = nf[2], x3v = nf[3], x4v = nf[4];
  __syncthreads();
  #pragma unroll
  for (int cc = 0; cc < 4; ++cc){
    int oc = h*32 + cc*8;
    u32x4 vh, vl;
    #pragma unroll
    for (int jj = 0; jj < 4; ++jj){
      int o = oc + jj*2;
      float ya = sFb0[o]   + sF0[o*5+0]*x0 + sF0[o*5+1]*x1v + sF0[o*5+2]*x2v + sF0[o*5+3]*x3v + sF0[o*5+4]*x4v;
      float yb = sFb0[o+1] + sF0[(o+1)*5+0]*x0 + sF0[(o+1)*5+1]*x1v + sF0[(o+1)*5+2]*x2v + sF0[(o+1)*5+3]*x3v + sF0[(o+1)*5+4]*x4v;
      ya = fmaxf(ya, 0.0f); yb = fmaxf(yb, 0.0f);
      unsigned short ha = f2b(ya), hb = f2b(yb);
      unsigned short la = f2b(ya - b2f(ha)), lb = f2b(yb - b2f(hb));
      vh[jj] = (unsigned)ha | ((unsigned)hb << 16);
      vl[jj] = (unsigned)la | ((unsigned)lb << 16);
    }
    unsigned off = swz((unsigned)(p*256 + oc*2));
    *(u32x4*)((char*)sXh + off) = vh;
    *(u32x4*)((char*)sXl + off) = vl;
  }
  __syncthreads();

  // L1: y1[64x128] = x1 * W1^T; wave w owns 32 channels, all 64 rows (mf4)
  const int wv = tid >> 6, lane = tid & 63;
  const int lrow = lane & 15, lk = lane >> 4;
  const unsigned short* w1hb = w1h + br*16384;
  const unsigned short* w1lb = w1l + br*16384;
  f32x4 zf = {0.0f, 0.0f, 0.0f, 0.0f};
  f32x4 acc[4][2];
  #pragma unroll
  for (int i=0;i<4;++i)
    #pragma unroll
    for (int j=0;j<2;++j) acc[i][j] = zf;

  #pragma unroll
  for (int ks = 0; ks < 4; ++ks){
    bf16x8 ah[4], al[4], bh[2], bl[2];
    #pragma unroll
    for (int mf = 0; mf < 4; ++mf){
      unsigned off = swz((unsigned)((mf*16 + lrow)*256 + ks*64 + lk*16));
      ah[mf] = *(bf16x8*)((char*)sXh + off);
      al[mf] = *(bf16x8*)((char*)sXl + off);
    }
    #pragma unroll
    for (int nf2 = 0; nf2 < 2; ++nf2){
      int o = wv*32 + nf2*16 + lrow;
      bh[nf2] = *(const bf16x8*)(w1hb + o*128 + ks*32 + lk*8);
      bl[nf2] = *(const bf16x8*)(w1lb + o*128 + ks*32 + lk*8);
    }
    #pragma unroll
    for (int mf = 0; mf < 4; ++mf)
      #pragma unroll
      for (int nf2 = 0; nf2 < 2; ++nf2){
        acc[mf][nf2] = __builtin_amdgcn_mfma_f32_16x16x32_bf16(ah[mf], bh[nf2], acc[mf][nf2], 0, 0, 0);
        acc[mf][nf2] = __builtin_amdgcn_mfma_f32_16x16x32_bf16(ah[mf], bl[nf2], acc[mf][nf2], 0, 0, 0);
        acc[mf][nf2] = __builtin_amdgcn_mfma_f32_16x16x32_bf16(al[mf], bh[nf2], acc[mf][nf2], 0, 0, 0);
      }
  }

  __syncthreads();   // all waves done reading x1 tiles
  // x2 = relu(bn1(y1)) -> sXh/sXl; lane pairs pack 2 channels per u32 write.
  #pragma unroll
  for (int nf2 = 0; nf2 < 2; ++nf2){
    int o = wv*32 + nf2*16 + lrow;
    float A = sA1[o], Bc = sB1[o];
    #pragma unroll
    for (int mf = 0; mf < 4; ++mf)
      #pragma unroll
      for (int r = 0; r < 4; ++r){
        float xv = fmaxf(fmaf(A, acc[mf][nf2][r], Bc), 0.0f);
        float xp = __shfl_xor(xv, 1);
        if (!(lrow & 1)){
          int mm = mf*16 + lk*4 + r;
          unsigned short h0 = f2b(xv), h1 = f2b(xp);
          unsigned short l0 = f2b(xv - b2f(h0)), l1 = f2b(xp - b2f(h1));
          unsigned off = swz((unsigned)(mm*256 + o*2));
          *(unsigned*)((char*)sXh + off) = (unsigned)h0 | ((unsigned)h1 << 16);
          *(unsigned*)((char*)sXl + off) = (unsigned)l0 | ((unsigned)l1 << 16);
        }
      }
  }
  __syncthreads();

  // L2: y2[64x256] = x2 * W2^T; wave w owns channels w*64..w*64+63 (2 chunks)
  const unsigned short* w2hb = w2h + br*32768;
  const unsigned short* w2lb = w2l + br*32768;
  float mxv[4][4];
  #pragma unroll
  for (int mf=0;mf<4;++mf)
    #pragma unroll
    for (int r=0;r<4;++r) mxv[mf][r] = 0.0f;   // relu >= 0

  #pragma unroll
  for (int nh = 0; nh < 2; ++nh){
    f32x4 a2[4][2];
    #pragma unroll
    for (int i=0;i<4;++i)
      #pragma unroll
      for (int j=0;j<2;++j) a2[i][j] = zf;
    #pragma unroll
    for (int ks = 0; ks < 4; ++ks){
      bf16x8 ah[4], al[4], bh[2], bl[2];
      #pragma unroll
      for (int mf = 0; mf < 4; ++mf){
        unsigned off = swz((unsigned)((mf*16 + lrow)*256 + ks*64 + lk*16));
        ah[mf] = *(bf16x8*)((char*)sXh + off);
        al[mf] = *(bf16x8*)((char*)sXl + off);
      }
      #pragma unroll
      for (int nf2 = 0; nf2 < 2; ++nf2){
        int o = wv*64 + nh*32 + nf2*16 + lrow;
        bh[nf2] = *(const bf16x8*)(w2hb + o*128 + ks*32 + lk*8);
        bl[nf2] = *(const bf16x8*)(w2lb + o*128 + ks*32 + lk*8);
      }
      #pragma unroll
      for (int mf = 0; mf < 4; ++mf)
        #pragma unroll
        for (int nf2 = 0; nf2 < 2; ++nf2){
          a2[mf][nf2] = __builtin_amdgcn_mfma_f32_16x16x32_bf16(ah[mf], bh[nf2], a2[mf][nf2], 0, 0, 0);
          a2[mf][nf2] = __builtin_amdgcn_mfma_f32_16x16x32_bf16(ah[mf], bl[nf2], a2[mf][nf2], 0, 0, 0);
          a2[mf][nf2] = __builtin_amdgcn_mfma_f32_16x16x32_bf16(al[mf], bh[nf2], a2[mf][nf2], 0, 0, 0);
        }
    }
    // bn2 + relu + running channel-max for this chunk
    #pragma unroll
    for (int mf = 0; mf < 4; ++mf)
      #pragma unroll
      for (int r = 0; r < 4; ++r){
        #pragma unroll
        for (int nf2 = 0; nf2 < 2; ++nf2){
          int o = wv*64 + nh*32 + nf2*16 + lrow;
          mxv[mf][r] = fmaxf(mxv[mf][r], fmaxf(fmaf(sA2[o], a2[mf][nf2][r], sB2[o]), 0.0f));
        }
      }
  }

  // per-wave max over its 64 channels -> sT[w][row]
  #pragma unroll
  for (int mf = 0; mf < 4; ++mf)
    #pragma unroll
    for (int r = 0; r < 4; ++r){
      float mx = mxv[mf][r];
      mx = fmaxf(mx, __shfl_xor(mx,1));
      mx = fmaxf(mx, __shfl_xor(mx,2));
      mx = fmaxf(mx, __shfl_xor(mx,4));
      mx = fmaxf(mx, __shfl_xor(mx,8));
      if (lrow == 0) sT[wv][mf*16 + lk*4 + r] = mx;
    }
  __syncthreads();
  if (tid < 64){
    float t0 = fmaxf(sT[0][tid], sT[1][tid]);
    float t1 = fmaxf(sT[2][tid], sT[3][tid]);
    tout[(size_t)br*MPOS + (size_t)blockIdx.x*64 + tid] = fmaxf(t0, t1);
  }
}

// ---------------- softmax + weighted sums ----------------
__global__ void k_final(const float* __restrict__ tbuf, const int* __restrict__ nn_idx,
                        const float* __restrict__ gpx, const float* __restrict__ gpy,
                        const float* __restrict__ gpz,
                        const float* __restrict__ fT, float* __restrict__ out){
  __shared__ float sw[4][64];
  const int wv = threadIdx.x >> 6, lane = threadIdx.x & 63;
  const int m = blockIdx.x*4 + wv, b = blockIdx.y;
  const size_t pos0 = (size_t)(b*NQ + m)*KNN;
  const int half = lane >> 5, kk = lane & 31;
  float tv = tbuf[(size_t)half*MPOS + pos0 + kk];
  float mx = tv;
  #pragma unroll
  for (int s=1;s<32;s<<=1) mx = fmaxf(mx, __shfl_xor(mx, s));
  float e = __expf(tv - mx);
  float sum = e;
  #pragma unroll
  for (int s=1;s<32;s<<=1) sum += __shfl_xor(sum, s);
  sw[wv][lane] = e / sum;    // lanes 0..31: wts (a), 32..63: wts1 (b)
  __syncthreads();
  const int* nn = nn_idx + pos0;
  float ax=0, ay=0, az=0, f0=0, f1=0;
  for (int k=0;k<KNN;++k){
    int idx = nn[k];
    float wa = sw[wv][k], wb = sw[wv][32+k];
    ax = fmaf(wa, gpx[b*NPTS+idx], ax);
    ay = fmaf(wa, gpy[b*NPTS+idx], ay);
    az = fmaf(wa, gpz[b*NPTS+idx], az);
    float2 fv = *(const float2*)(fT + ((size_t)b*NPTS + idx)*CF + lane*2);
    f0 = fmaf(wb, fv.x, f0);
    f1 = fmaf(wb, fv.y, f1);
  }
  if (lane == 0){
    out[((size_t)b*131 + 0)*NQ + m] = ax;
    out[((size_t)b*131 + 1)*NQ + m] = ay;
    out[((size_t)b*131 + 2)*NQ + m] = az;
  }
  out[((size_t)b*131 + 3 + lane*2)*NQ + m] = f0;
  out[((size_t)b*131 + 4 + lane*2)*NQ + m] = f1;
}

extern "C" void kernel_launch(void* const* d_in, const int* in_sizes, int n_in,
                              void* d_out, int out_size, void* d_ws, size_t ws_size,
                              hipStream_t stream){
  const float* points1   = (const float*)d_in[0];
  const float* points2   = (const float*)d_in[1];
  const float* features1 = (const float*)d_in[2];
  const float* features2 = (const float*)d_in[3];
  const int*   randidx   = (const int*)d_in[4];
  const float* aw0 = (const float*)d_in[6];
  const float* ag0 = (const float*)d_in[8];
  const float* abe0= (const float*)d_in[9];
  const float* aw1 = (const float*)d_in[10];
  const float* ag1 = (const float*)d_in[12];
  const float* abe1= (const float*)d_in[13];
  const float* aw2 = (const float*)d_in[14];
  const float* ag2 = (const float*)d_in[16];
  const float* abe2= (const float*)d_in[17];
  const float* bw0 = (const float*)d_in[18];
  const float* bg0 = (const float*)d_in[20];
  const float* bbe0= (const float*)d_in[21];
  const float* bw1 = (const float*)d_in[22];
  const float* bg1 = (const float*)d_in[24];
  const float* bbe1= (const float*)d_in[25];
  const float* bw2 = (const float*)d_in[26];
  const float* bg2 = (const float*)d_in[28];
  const float* bbe2= (const float*)d_in[29];

  char* ws = (char*)d_ws;
  float* px   = (float*)(ws + 0);
  float* py   = (float*)(ws + 65536);
  float* pz   = (float*)(ws + 131072);
  float* fT   = (float*)(ws + 196608);                    // 8MB f32 [b][p][c]
  unsigned short* w1h = (unsigned short*)(ws + 8585216);  // 64KB
  unsigned short* w2h = (unsigned short*)(ws + 8650752);  // 128KB
  unsigned short* w1l = (unsigned short*)(ws + 8781824);  // 64KB
  unsigned short* w2l = (unsigned short*)(ws + 8847360);  // 128KB
  int*   nn   = (int*)(ws + 8978432);                     // 1MB
  float* newf = (float*)(ws + 10027008);                  // 5.24MB [pos][5]
  float* tbuf = (float*)(ws + 15269888);                  // 2MB [branch][pos]
  float* mom  = (float*)(ws + 17367040);                  // stats block
  float* y1s = mom + 20;  float* y1q = y1s + 256;
  float* y2s = y1q + 256; float* y2q = y2s + 512;

  hipMemsetAsync(mom, 0, 6224, stream);
  k_prep<<<dim3(448), 256, 0, stream>>>(points1, points2, aw1, bw1, aw2, bw2,
      px, py, pz, w1h, w1l, w2h, w2l);
  k_transpose_f<<<dim3(256,4,2), 256, 0, stream>>>(features1, features2, fT);
  k_knn<<<dim3(256,2), 1024, 0, stream>>>(px, py, pz, randidx, nn, newf);
  k_fdot<<<dim3(1024,2), 256, 0, stream>>>(fT, randidx, nn, newf);
  k_moments<<<dim3(1024), 256, 0, stream>>>(newf, mom);
  k_pass<1><<<dim3(2048,2), 256, 0, stream>>>(newf, aw0,bw0, ag0,bg0, abe0,bbe0,
      ag1,bg1, abe1,bbe1, w1h,w2h, mom, y1s,y1q,y2s,y2q);
  k_pass<2><<<dim3(2048,2), 256, 0, stream>>>(newf, aw0,bw0, ag0,bg0, abe0,bbe0,
      ag1,bg1, abe1,bbe1, w1h,w2h, mom, y1s,y1q,y2s,y2q);
  k_pass3<<<dim3(4096,2), 256, 0, stream>>>(newf, aw0,bw0, ag0,bg0, abe0,bbe0,
      ag1,bg1, abe1,bbe1, ag2,bg2, abe2,bbe2, w1h,w1l,w2h,w2l, mom,
      y1s,y1q,y2s,y2q, tbuf);
  k_final<<<dim3(1024,2), 256, 0, stream>>>(tbuf, nn, px, py, pz, fT, (float*)d_out);
}

// Round 15
// 784.835 us; speedup vs baseline: 1.1251x; 1.1251x over previous
//
#include <hip/hip_runtime.h>

#define NB 2
#define NQ 4096
#define NPTS 8192
#define KNN 32
#define CF 128
#define MPOS (NB*NQ*KNN)
#define EPSV 1e-5f

typedef __attribute__((ext_vector_type(8))) short bf16x8;
typedef __attribute__((ext_vector_type(4))) float f32x4;
typedef __attribute__((ext_vector_type(4))) unsigned int u32x4;
typedef unsigned long long u64;

__device__ __forceinline__ unsigned short f2b(float f){
  unsigned u = __float_as_uint(f);
  return (unsigned short)((u + 0x7fffu + ((u >> 16) & 1u)) >> 16);
}
__device__ __forceinline__ float b2f(unsigned short h){
  return __uint_as_float(((unsigned)h) << 16);
}
// XOR swizzle for LDS tiles with 256B rows (bf16[128] rows).
__device__ __forceinline__ unsigned swz(unsigned byte){
  return byte ^ (((byte >> 8) & 7u) << 4);
}
// fragment-packed weight index: row-tile otile=row>>4, ks=col>>5,
// lane=( (col>>3)&3 )*16 + (row&15), elem=col&7  -> coalesced 1KB/frag load.
__device__ __forceinline__ int wpack(int row, int col){
  return (((row >> 4)*4 + (col >> 5))*64 + ((col >> 3) & 3)*16 + (row & 15))*8 + (col & 7);
}

// ---------------- prep: points SoA + weights to packed bf16 hi/lo ----------
__global__ void k_prep(const float* __restrict__ p1, const float* __restrict__ p2,
                       const float* __restrict__ aw1, const float* __restrict__ bw1,
                       const float* __restrict__ aw2, const float* __restrict__ bw2,
                       float* __restrict__ px, float* __restrict__ py, float* __restrict__ pz,
                       unsigned short* __restrict__ w1h, unsigned short* __restrict__ w1l,
                       unsigned short* __restrict__ w2h, unsigned short* __restrict__ w2l){
  int t = blockIdx.x*256 + threadIdx.x;
  if (t < NB*NPTS){
    int b = t / NPTS, p = t - b*NPTS;
    const float* s = (p < NQ) ? p1 : p2;
    int pp = (p < NQ) ? p : p - NQ;
    px[t] = s[(b*3+0)*NQ + pp];
    py[t] = s[(b*3+1)*NQ + pp];
    pz[t] = s[(b*3+2)*NQ + pp];
  } else {
    int u = t - NB*NPTS;
    if (u < 32768){
      int brn = u >> 14, i = u & 16383;
      float w = brn ? bw1[i] : aw1[i];
      unsigned short hi = f2b(w);
      int pidx = brn*16384 + wpack(i >> 7, i & 127);
      w1h[pidx] = hi; w1l[pidx] = f2b(w - b2f(hi));
    } else {
      int v = u - 32768;
      if (v < 65536){
        int brn = v >> 15, i = v & 32767;
        float w = brn ? bw2[i] : aw2[i];
        unsigned short hi = f2b(w);
        int pidx = brn*32768 + wpack(i >> 7, i & 127);
        w2h[pidx] = hi; w2l[pidx] = f2b(w - b2f(hi));
      }
    }
  }
}

// ---------------- prep: feature transpose to [b][p][c] f32 ----------------
__global__ void k_transpose_f(const float* __restrict__ f1, const float* __restrict__ f2,
                              float* __restrict__ fT){
  __shared__ float tile[32][33];
  int p0 = blockIdx.x*32, c0 = blockIdx.y*32, b = blockIdx.z;
  const float* s = (p0 < NQ) ? f1 : f2;
  int pp0 = (p0 < NQ) ? p0 : p0 - NQ;
  int tx = threadIdx.x & 31, ty = threadIdx.x >> 5;
  #pragma unroll
  for (int i = 0; i < 32; i += 8)
    tile[ty+i][tx] = s[((size_t)b*CF + c0+ty+i)*NQ + pp0 + tx];
  __syncthreads();
  #pragma unroll
  for (int i = 0; i < 32; i += 8)
    fT[((size_t)b*NPTS + p0+ty+i)*CF + c0 + tx] = tile[tx][ty+i];
}

// ---------------- KNN: one wave per query, 16 waves/block ----------------
// Replicates the reference d2 formula in strict f32 (no FMA).
__global__ __launch_bounds__(1024,1) void k_knn(const float* __restrict__ gpx, const float* __restrict__ gpy,
        const float* __restrict__ gpz, const int* __restrict__ randidx,
        int* __restrict__ nn_idx, float* __restrict__ newf){
  __shared__ float4 sp[NPTS];
  __shared__ u64 sbuf[16][192];
  const int b = blockIdx.y;
  for (int i = threadIdx.x; i < NPTS; i += 1024){
    float x = gpx[b*NPTS+i], y = gpy[b*NPTS+i], z = gpz[b*NPTS+i];
    float sq = __fadd_rn(__fadd_rn(__fmul_rn(x,x), __fmul_rn(y,y)), __fmul_rn(z,z));
    sp[i] = make_float4(x, y, z, sq);
  }
  __syncthreads();
  const int wv = threadIdx.x >> 6, lane = threadIdx.x & 63;
  const int m = blockIdx.x*16 + wv;
  const int ridx = randidx[m];
  const float4 Q = sp[ridx];
  const float qx = Q.x, qy = Q.y, qz = Q.z, s1q = Q.w;
  u64* buf = sbuf[wv];

  u64 top = ~0ull;
  float thr = __builtin_inff();
  int cnt = 0;

  auto flush = [&](){
    u64 e0 = (lane       < cnt) ? buf[lane]     : ~0ull;
    u64 e1 = (lane + 64  < cnt) ? buf[lane+64]  : ~0ull;
    u64 e2 = (lane + 128 < cnt) ? buf[lane+128] : ~0ull;
    u64 e3 = (lane < KNN) ? top : ~0ull;
    #define SWP(a,b) { u64 lo_ = (a<b)?a:b; u64 hi_ = (a<b)?b:a; a=lo_; b=hi_; }
    SWP(e0,e1) SWP(e2,e3) SWP(e0,e2) SWP(e1,e3) SWP(e1,e2)
    #undef SWP
    u64 newtop = ~0ull, v = 0;
    for (int i = 0; i < KNN; ++i){
      v = e0;
      #pragma unroll
      for (int s = 1; s < 64; s <<= 1){
        u64 o = __shfl_xor(v, s);
        if (o < v) v = o;
      }
      bool win = (e0 == v);
      e0 = win ? e1 : e0; e1 = win ? e2 : e1; e2 = win ? e3 : e2;
      e3 = win ? ~0ull : e3;
      newtop = (lane == i) ? v : newtop;
    }
    top = newtop;
    unsigned k32 = (unsigned)(v >> 32);
    unsigned uu = (k32 & 0x80000000u) ? (k32 ^ 0x80000000u) : ~k32;
    thr = __uint_as_float(uu);
    cnt = 0;
  };

  for (int c = 0; c < NPTS/64; ++c){
    if (cnt > 128) flush();
    int j = c*64 + lane;
    float4 P = sp[j];
    float dot = __fadd_rn(__fadd_rn(__fmul_rn(qx,P.x), __fmul_rn(qy,P.y)), __fmul_rn(qz,P.z));
    float d   = __fsub_rn(__fadd_rn(s1q, P.w), __fmul_rn(2.0f, dot));
    bool pred = (d <= thr);
    u64 mask = __ballot(pred);
    if (mask){
      if (pred){
        int rank = __popcll(mask & ((1ull << lane) - 1ull));
        unsigned u = __float_as_uint(d);
        unsigned key = u ^ ((unsigned)((int)u >> 31) | 0x80000000u);
        buf[cnt + rank] = ((u64)key << 32) | (unsigned)j;
      }
      cnt += __popcll(mask);
    }
  }
  flush();

  if (lane < KNN){
    int idx = (int)(unsigned)(top & 0xffffffffull);
    size_t pos = (size_t)(b*NQ + m)*KNN + lane;
    nn_idx[pos] = idx;
    float4 P = sp[idx];
    float rx = P.x-qx, ry = P.y-qy, rz = P.z-qz;
    float dd = sqrtf(rx*rx + ry*ry + rz*rz);
    float* nf = newf + pos*5;
    nf[0] = rx; nf[1] = ry; nf[2] = rz; nf[3] = dd;
  }
}

// ---------------- fdot channel: lane=(k,half), 64 ch per lane ----------------
__global__ void k_fdot(const float* __restrict__ fT, const int* __restrict__ randidx,
                       const int* __restrict__ nn_idx, float* __restrict__ newf){
  const int wv = threadIdx.x >> 6, lane = threadIdx.x & 63;
  const int m = blockIdx.x*4 + wv, b = blockIdx.y;
  const int k = lane >> 1, half = lane & 1;
  const int ridx = randidx[m];
  const int idx = nn_idx[(size_t)(b*NQ + m)*KNN + k];
  const float* f1p = fT + ((size_t)b*NPTS + ridx)*CF + half*64;
  const float* gp  = fT + ((size_t)b*NPTS + idx )*CF + half*64;
  float s = 0.0f;
  #pragma unroll
  for (int c = 0; c < 16; ++c){
    float4 a = *(const float4*)(f1p + c*4);
    float4 g = *(const float4*)(gp  + c*4);
    s += a.x*g.x + a.y*g.y + a.z*g.z + a.w*g.w;
  }
  s += __shfl_xor(s, 1);
  if (half == 0)
    newf[((size_t)(b*NQ + m)*KNN + k)*5 + 4] = s;
}

// ---------------- moments of newf (for analytic y0 stats) ----------------
__global__ void k_moments(const float* __restrict__ newf, float* __restrict__ mom){
  float v[20];
  #pragma unroll
  for (int i = 0; i < 20; ++i) v[i] = 0.0f;
  int p = blockIdx.x*256 + threadIdx.x;
  if (p < MPOS){
    const float* nf = newf + (size_t)p*5;
    float x0=nf[0], x1=nf[1], x2=nf[2], x3=nf[3], x4=nf[4];
    v[0]=x0; v[1]=x1; v[2]=x2; v[3]=x3; v[4]=x4;
    v[5]=x0*x0; v[6]=x0*x1; v[7]=x0*x2; v[8]=x0*x3; v[9]=x0*x4;
    v[10]=x1*x1; v[11]=x1*x2; v[12]=x1*x3; v[13]=x1*x4;
    v[14]=x2*x2; v[15]=x2*x3; v[16]=x2*x4;
    v[17]=x3*x3; v[18]=x3*x4; v[19]=x4*x4;
  }
  #pragma unroll
  for (int i = 0; i < 20; ++i){
    float t = v[i];
    #pragma unroll
    for (int sh = 1; sh < 64; sh <<= 1) t += __shfl_xor(t, sh);
    v[i] = t;
  }
  __shared__ float red[4][20];
  int wv = threadIdx.x >> 6, lane = threadIdx.x & 63;
  if (lane == 0){
    #pragma unroll
    for (int i = 0; i < 20; ++i) red[wv][i] = v[i];
  }
  __syncthreads();
  if (threadIdx.x < 20)
    atomicAdd(&mom[threadIdx.x],
              red[0][threadIdx.x]+red[1][threadIdx.x]+red[2][threadIdx.x]+red[3][threadIdx.x]);
}

// ---------------- stat passes: 256-thread blocks, BM=128 ----------------
// PASS 1: L0+L1, accumulate y1 sum/sumsq.  PASS 2: chain to y2, sum/sumsq.
// launch_bounds(256,3); L2 stat GEMM in FOUR 32-channel chunks (a2[4][2]).
// Weights read via fragment-packed layout -> coalesced 1KB wave loads.
template<int PASS>
__global__ __launch_bounds__(256,3) void k_pass(
    const float* __restrict__ newf,
    const float* __restrict__ aw0, const float* __restrict__ bw0,
    const float* __restrict__ ag0, const float* __restrict__ bg0,
    const float* __restrict__ abe0, const float* __restrict__ bbe0,
    const float* __restrict__ ag1, const float* __restrict__ bg1,
    const float* __restrict__ abe1, const float* __restrict__ bbe1,
    const unsigned short* __restrict__ w1b, const unsigned short* __restrict__ w2b,
    const float* __restrict__ mom,
    float* __restrict__ y1s, float* __restrict__ y1q,
    float* __restrict__ y2s, float* __restrict__ y2q)
{
  __shared__ unsigned short sX[128*128];   // x1 then x2 tile, swizzled 256B rows
  __shared__ float sF0[128*5], sFb0[128];
  __shared__ float sA1[128], sB1[128];
  __shared__ float sStat[512];

  const int tid = threadIdx.x;
  const int br = blockIdx.y;
  const float invM = 1.0f / (float)MPOS;

  if (tid < 128){
    const float* w0 = (br ? bw0 : aw0) + tid*5;
    float g  = (br ? bg0 : ag0)[tid];
    float be = (br ? bbe0: abe0)[tid];
    float w[5], m5[5];
    #pragma unroll
    for (int i=0;i<5;++i){ w[i]=w0[i]; m5[i]=mom[i]*invM; }
    float mu = 0;
    #pragma unroll
    for (int i=0;i<5;++i) mu += w[i]*m5[i];
    const int I[15] = {0,0,0,0,0,1,1,1,1,2,2,2,3,3,4};
    const int J[15] = {0,1,2,3,4,1,2,3,4,2,3,4,3,4,4};
    float e2 = 0;
    #pragma unroll
    for (int t2=0;t2<15;++t2){
      float c = (I[t2]==J[t2]) ? 1.0f : 2.0f;
      e2 += c * w[I[t2]] * w[J[t2]] * (mom[5+t2]*invM);
    }
    float var = fmaxf(e2 - mu*mu, 0.0f);
    float A = g * rsqrtf(var + EPSV);
    #pragma unroll
    for (int i=0;i<5;++i) sF0[tid*5+i] = A*w[i];
    sFb0[tid] = be - A*mu;
  }
  if (PASS >= 2 && tid < 128){
    float s = y1s[br*128+tid]*invM, q = y1q[br*128+tid]*invM;
    float var = fmaxf(q - s*s, 0.0f);
    float g = (br ? bg1 : ag1)[tid], be = (br ? bbe1 : abe1)[tid];
    float A = g*rsqrtf(var + EPSV);
    sA1[tid] = A; sB1[tid] = be - A*s;
  }
  sStat[tid] = 0.0f; sStat[256+tid] = 0.0f;

  const int p = tid >> 1, h = tid & 1;
  const size_t gp = (size_t)blockIdx.x*128 + p;
  const float* nf = newf + gp*5;
  float x0 = nf[0], x1v = nf[1], x2v = nf[2], x3v = nf[3], x4v = nf[4];
  __syncthreads();
  #pragma unroll
  for (int cc = 0; cc < 8; ++cc){
    int oc = h*64 + cc*8;
    u32x4 vv;
    #pragma unroll
    for (int jj = 0; jj < 4; ++jj){
      int o = oc + jj*2;
      float ya = sFb0[o]   + sF0[o*5+0]*x0 + sF0[o*5+1]*x1v + sF0[o*5+2]*x2v + sF0[o*5+3]*x3v + sF0[o*5+4]*x4v;
      float yb = sFb0[o+1] + sF0[(o+1)*5+0]*x0 + sF0[(o+1)*5+1]*x1v + sF0[(o+1)*5+2]*x2v + sF0[(o+1)*5+3]*x3v + sF0[(o+1)*5+4]*x4v;
      vv[jj] = (unsigned)f2b(fmaxf(ya,0.0f)) | ((unsigned)f2b(fmaxf(yb,0.0f)) << 16);
    }
    *(u32x4*)((char*)sX + swz((unsigned)(p*256 + oc*2))) = vv;
  }
  __syncthreads();

  const int wv = tid >> 6, lane = tid & 63;
  const int mb = wv >> 1, nb = wv & 1;
  const int lrow = lane & 15, lk = lane >> 4;
  const unsigned short* w1g = w1b + br*16384;
  f32x4 zf = {0.0f, 0.0f, 0.0f, 0.0f};
  f32x4 acc[4][4];
  #pragma unroll
  for (int i=0;i<4;++i)
    #pragma unroll
    for (int j=0;j<4;++j) acc[i][j] = zf;

  #pragma unroll
  for (int ks = 0; ks < 4; ++ks){
    bf16x8 af[4], bfr[4];
    #pragma unroll
    for (int mf = 0; mf < 4; ++mf){
      int row = mb*64 + mf*16 + lrow;
      af[mf] = *(bf16x8*)((char*)sX + swz((unsigned)(row*256 + ks*64 + lk*16)));
    }
    #pragma unroll
    for (int nf2 = 0; nf2 < 4; ++nf2){
      int otile = nb*4 + nf2;
      bfr[nf2] = *(const bf16x8*)(w1g + ((otile*4 + ks)*64 + lane)*8);
    }
    #pragma unroll
    for (int mf = 0; mf < 4; ++mf)
      #pragma unroll
      for (int nf2 = 0; nf2 < 4; ++nf2)
        acc[mf][nf2] = __builtin_amdgcn_mfma_f32_16x16x32_bf16(af[mf], bfr[nf2], acc[mf][nf2], 0, 0, 0);
  }

  if (PASS == 1){
    #pragma unroll
    for (int nf2 = 0; nf2 < 4; ++nf2){
      float s = 0, q = 0;
      #pragma unroll
      for (int mf=0;mf<4;++mf)
        #pragma unroll
        for (int r=0;r<4;++r){ float v2 = acc[mf][nf2][r]; s += v2; q += v2*v2; }
      s += __shfl_xor(s,16); s += __shfl_xor(s,32);
      q += __shfl_xor(q,16); q += __shfl_xor(q,32);
      if (lane < 16){
        int o = nb*64 + nf2*16 + lrow;
        atomicAdd(&sStat[o], s);
        atomicAdd(&sStat[256+o], q);
      }
    }
    __syncthreads();
    if (tid < 128){
      atomicAdd(&y1s[br*128 + tid], sStat[tid]);
      atomicAdd(&y1q[br*128 + tid], sStat[256+tid]);
    }
    return;
  }

  __syncthreads();   // all waves done reading sX(x1)
  #pragma unroll
  for (int nf2 = 0; nf2 < 4; ++nf2){
    int o = nb*64 + nf2*16 + lrow;
    float A = sA1[o], Bc = sB1[o];
    #pragma unroll
    for (int mf = 0; mf < 4; ++mf)
      #pragma unroll
      for (int r = 0; r < 4; ++r){
        float xv = fmaxf(fmaf(A, acc[mf][nf2][r], Bc), 0.0f);
        int mm = mb*64 + mf*16 + lk*4 + r;
        *(unsigned short*)((char*)sX + swz((unsigned)(mm*256 + o*2))) = f2b(xv);
      }
  }
  __syncthreads();

  // L2 stat GEMM in FOUR 32-channel chunks (a2[4][2] keeps reg demand low)
  const unsigned short* w2 = w2b + br*32768;
  #pragma unroll
  for (int nh = 0; nh < 4; ++nh){
    f32x4 a2[4][2];
    #pragma unroll
    for (int i=0;i<4;++i)
      #pragma unroll
      for (int j=0;j<2;++j) a2[i][j] = zf;
    #pragma unroll
    for (int ks = 0; ks < 4; ++ks){
      bf16x8 af[4];
      #pragma unroll
      for (int mf = 0; mf < 4; ++mf){
        int row = mb*64 + mf*16 + lrow;
        af[mf] = *(bf16x8*)((char*)sX + swz((unsigned)(row*256 + ks*64 + lk*16)));
      }
      bf16x8 bw2f[2];
      #pragma unroll
      for (int nf2 = 0; nf2 < 2; ++nf2){
        int otile = nb*8 + nh*2 + nf2;
        bw2f[nf2] = *(const bf16x8*)(w2 + ((otile*4 + ks)*64 + lane)*8);
      }
      #pragma unroll
      for (int mf = 0; mf < 4; ++mf)
        #pragma unroll
        for (int nf2 = 0; nf2 < 2; ++nf2)
          a2[mf][nf2] = __builtin_amdgcn_mfma_f32_16x16x32_bf16(af[mf], bw2f[nf2], a2[mf][nf2], 0, 0, 0);
    }
    #pragma unroll
    for (int nf2 = 0; nf2 < 2; ++nf2){
      float s = 0, q = 0;
      #pragma unroll
      for (int mf=0;mf<4;++mf)
        #pragma unroll
        for (int r=0;r<4;++r){ float v2 = a2[mf][nf2][r]; s += v2; q += v2*v2; }
      s += __shfl_xor(s,16); s += __shfl_xor(s,32);
      q += __shfl_xor(q,16); q += __shfl_xor(q,32);
      if (lane < 16){
        int o = nb*128 + nh*32 + nf2*16 + lrow;
        atomicAdd(&sStat[o], s);
        atomicAdd(&sStat[256+o], q);
      }
    }
  }
  __syncthreads();
  atomicAdd(&y2s[br*256 + tid], sStat[tid]);
  atomicAdd(&y2q[br*256 + tid], sStat[256+tid]);
}

// ---------------- final pass: split-bf16, 256-thread blocks, BM=64 ----------
// launch_bounds(256,3): verified optimum (R9/R11/R13). Packed-weight loads.
__global__ __launch_bounds__(256,3) void k_pass3(
    const float* __restrict__ newf,
    const float* __restrict__ aw0, const float* __restrict__ bw0,
    const float* __restrict__ ag0, const float* __restrict__ bg0,
    const float* __restrict__ abe0, const float* __restrict__ bbe0,
    const float* __restrict__ ag1, const float* __restrict__ bg1,
    const float* __restrict__ abe1, const float* __restrict__ bbe1,
    const float* __restrict__ ag2, const float* __restrict__ bg2,
    const float* __restrict__ abe2, const float* __restrict__ bbe2,
    const unsigned short* __restrict__ w1h, const unsigned short* __restrict__ w1l,
    const unsigned short* __restrict__ w2h, const unsigned short* __restrict__ w2l,
    const float* __restrict__ mom,
    const float* __restrict__ y1s, const float* __restrict__ y1q,
    const float* __restrict__ y2s, const float* __restrict__ y2q,
    float* __restrict__ tout)
{
  __shared__ unsigned short sXh[64*128], sXl[64*128];
  __shared__ float sF0[128*5], sFb0[128];
  __shared__ float sA1[128], sB1[128];
  __shared__ float sA2[256], sB2[256];
  __shared__ float sT[4][64];

  const int tid = threadIdx.x;
  const int br = blockIdx.y;
  const float invM = 1.0f / (float)MPOS;

  if (tid < 128){
    const float* w0 = (br ? bw0 : aw0) + tid*5;
    float g  = (br ? bg0 : ag0)[tid];
    float be = (br ? bbe0: abe0)[tid];
    float w[5], m5[5];
    #pragma unroll
    for (int i=0;i<5;++i){ w[i]=w0[i]; m5[i]=mom[i]*invM; }
    float mu = 0;
    #pragma unroll
    for (int i=0;i<5;++i) mu += w[i]*m5[i];
    const int I[15] = {0,0,0,0,0,1,1,1,1,2,2,2,3,3,4};
    const int J[15] = {0,1,2,3,4,1,2,3,4,2,3,4,3,4,4};
    float e2 = 0;
    #pragma unroll
    for (int t2=0;t2<15;++t2){
      float c = (I[t2]==J[t2]) ? 1.0f : 2.0f;
      e2 += c * w[I[t2]] * w[J[t2]] * (mom[5+t2]*invM);
    }
    float var = fmaxf(e2 - mu*mu, 0.0f);
    float A = g * rsqrtf(var + EPSV);
    #pragma unroll
    for (int i=0;i<5;++i) sF0[tid*5+i] = A*w[i];
    sFb0[tid] = be - A*mu;

    float s1 = y1s[br*128+tid]*invM, q1 = y1q[br*128+tid]*invM;
    float var1 = fmaxf(q1 - s1*s1, 0.0f);
    float g1 = (br ? bg1 : ag1)[tid], be1 = (br ? bbe1 : abe1)[tid];
    float A1 = g1*rsqrtf(var1 + EPSV);
    sA1[tid] = A1; sB1[tid] = be1 - A1*s1;
  }
  {
    int c2 = tid;           // 256 threads cover 256 channels
    float s = y2s[br*256+c2]*invM, q = y2q[br*256+c2]*invM;
    float var = fmaxf(q - s*s, 0.0f);
    float g = (br ? bg2 : ag2)[c2], be = (br ? bbe2 : abe2)[c2];
    float A = g*rsqrtf(var + EPSV);
    sA2[c2] = A; sB2[c2] = be - A*s;
  }

  // x1 tile: 4 threads per position, 32 channels each; split hi/lo
  const int p = tid >> 2, h = tid & 3;
  const size_t gp = (size_t)blockIdx.x*64 + p;
  const float* nf = newf + gp*5;
  float x0 = nf[0], x1v = nf[1], x2v = nf[2], x3v = nf[3], x4v = nf[4];
  __syncthreads();
  #pragma unroll
  for (int cc = 0; cc < 4; ++cc){
    int oc = h*32 + cc*8;
    u32x4 vh, vl;
    #pragma unroll
    for (int jj = 0; jj < 4; ++jj){
      int o = oc + jj*2;
      float ya = sFb0[o]   + sF0[o*5+0]*x0 + sF0[o*5+1]*x1v + sF0[o*5+2]*x2v + sF0[o*5+3]*x3v + sF0[o*5+4]*x4v;
      float yb = sFb0[o+1] + sF0[(o+1)*5+0]*x0 + sF0[(o+1)*5+1]*x1v + sF0[(o+1)*5+2]*x2v + sF0[(o+1)*5+3]*x3v + sF0[(o+1)*5+4]*x4v;
      ya = fmaxf(ya, 0.0f); yb = fmaxf(yb, 0.0f);
      unsigned short ha = f2b(ya), hb = f2b(yb);
      unsigned short la = f2b(ya - b2f(ha)), lb = f2b(yb - b2f(hb));
      vh[jj] = (unsigned)ha | ((unsigned)hb << 16);
      vl[jj] = (unsigned)la | ((unsigned)lb << 16);
    }
    unsigned off = swz((unsigned)(p*256 + oc*2));
    *(u32x4*)((char*)sXh + off) = vh;
    *(u32x4*)((char*)sXl + off) = vl;
  }
  __syncthreads();

  // L1: y1[64x128] = x1 * W1^T; wave w owns 32 channels, all 64 rows (mf4)
  const int wv = tid >> 6, lane = tid & 63;
  const int lrow = lane & 15, lk = lane >> 4;
  const unsigned short* w1hb = w1h + br*16384;
  const unsigned short* w1lb = w1l + br*16384;
  f32x4 zf = {0.0f, 0.0f, 0.0f, 0.0f};
  f32x4 acc[4][2];
  #pragma unroll
  for (int i=0;i<4;++i)
    #pragma unroll
    for (int j=0;j<2;++j) acc[i][j] = zf;

  #pragma unroll
  for (int ks = 0; ks < 4; ++ks){
    bf16x8 ah[4], al[4], bh[2], bl[2];
    #pragma unroll
    for (int mf = 0; mf < 4; ++mf){
      unsigned off = swz((unsigned)((mf*16 + lrow)*256 + ks*64 + lk*16));
      ah[mf] = *(bf16x8*)((char*)sXh + off);
      al[mf] = *(bf16x8*)((char*)sXl + off);
    }
    #pragma unroll
    for (int nf2 = 0; nf2 < 2; ++nf2){
      int otile = wv*2 + nf2;
      bh[nf2] = *(const bf16x8*)(w1hb + ((otile*4 + ks)*64 + lane)*8);
      bl[nf2] = *(const bf16x8*)(w1lb + ((otile*4 + ks)*64 + lane)*8);
    }
    #pragma unroll
    for (int mf = 0; mf < 4; ++mf)
      #pragma unroll
      for (int nf2 = 0; nf2 < 2; ++nf2){
        acc[mf][nf2] = __builtin_amdgcn_mfma_f32_16x16x32_bf16(ah[mf], bh[nf2], acc[mf][nf2], 0, 0, 0);
        acc[mf][nf2] = __builtin_amdgcn_mfma_f32_16x16x32_bf16(ah[mf], bl[nf2], acc[mf][nf2], 0, 0, 0);
        acc[mf][nf2] = __builtin_amdgcn_mfma_f32_16x16x32_bf16(al[mf], bh[nf2], acc[mf][nf2], 0, 0, 0);
      }
  }

  __syncthreads();   // all waves done reading x1 tiles
  // x2 = relu(bn1(y1)) -> sXh/sXl (C/D: col=lane&15, row=(lane>>4)*4+r)
  #pragma unroll
  for (int nf2 = 0; nf2 < 2; ++nf2){
    int o = wv*32 + nf2*16 + lrow;
    float A = sA1[o], Bc = sB1[o];
    #pragma unroll
    for (int mf = 0; mf < 4; ++mf)
      #pragma unroll
      for (int r = 0; r < 4; ++r){
        float xv = fmaxf(fmaf(A, acc[mf][nf2][r], Bc), 0.0f);
        int mm = mf*16 + lk*4 + r;
        unsigned short hi = f2b(xv);
        unsigned short lo = f2b(xv - b2f(hi));
        unsigned off = swz((unsigned)(mm*256 + o*2));
        *(unsigned short*)((char*)sXh + off) = hi;
        *(unsigned short*)((char*)sXl + off) = lo;
      }
  }
  __syncthreads();

  // L2: y2[64x256] = x2 * W2^T; wave w owns channels w*64..w*64+63 (2 chunks)
  const unsigned short* w2hb = w2h + br*32768;
  const unsigned short* w2lb = w2l + br*32768;
  float mxv[4][4];
  #pragma unroll
  for (int mf=0;mf<4;++mf)
    #pragma unroll
    for (int r=0;r<4;++r) mxv[mf][r] = 0.0f;   // relu >= 0

  #pragma unroll
  for (int nh = 0; nh < 2; ++nh){
    f32x4 a2[4][2];
    #pragma unroll
    for (int i=0;i<4;++i)
      #pragma unroll
      for (int j=0;j<2;++j) a2[i][j] = zf;
    #pragma unroll
    for (int ks = 0; ks < 4; ++ks){
      bf16x8 ah[4], al[4], bh[2], bl[2];
      #pragma unroll
      for (int mf = 0; mf < 4; ++mf){
        unsigned off = swz((unsigned)((mf*16 + lrow)*256 + ks*64 + lk*16));
        ah[mf] = *(bf16x8*)((char*)sXh + off);
        al[mf] = *(bf16x8*)((char*)sXl + off);
      }
      #pragma unroll
      for (int nf2 = 0; nf2 < 2; ++nf2){
        int otile = wv*4 + nh*2 + nf2;
        bh[nf2] = *(const bf16x8*)(w2hb + ((otile*4 + ks)*64 + lane)*8);
        bl[nf2] = *(const bf16x8*)(w2lb + ((otile*4 + ks)*64 + lane)*8);
      }
      #pragma unroll
      for (int mf = 0; mf < 4; ++mf)
        #pragma unroll
        for (int nf2 = 0; nf2 < 2; ++nf2){
          a2[mf][nf2] = __builtin_amdgcn_mfma_f32_16x16x32_bf16(ah[mf], bh[nf2], a2[mf][nf2], 0, 0, 0);
          a2[mf][nf2] = __builtin_amdgcn_mfma_f32_16x16x32_bf16(ah[mf], bl[nf2], a2[mf][nf2], 0, 0, 0);
          a2[mf][nf2] = __builtin_amdgcn_mfma_f32_16x16x32_bf16(al[mf], bh[nf2], a2[mf][nf2], 0, 0, 0);
        }
    }
    // bn2 + relu + running channel-max for this chunk
    #pragma unroll
    for (int mf = 0; mf < 4; ++mf)
      #pragma unroll
      for (int r = 0; r < 4; ++r){
        #pragma unroll
        for (int nf2 = 0; nf2 < 2; ++nf2){
          int o = wv*64 + nh*32 + nf2*16 + lrow;
          mxv[mf][r] = fmaxf(mxv[mf][r], fmaxf(fmaf(sA2[o], a2[mf][nf2][r], sB2[o]), 0.0f));
        }
      }
  }

  // per-wave max over its 64 channels -> sT[w][row]
  #pragma unroll
  for (int mf = 0; mf < 4; ++mf)
    #pragma unroll
    for (int r = 0; r < 4; ++r){
      float mx = mxv[mf][r];
      mx = fmaxf(mx, __shfl_xor(mx,1));
      mx = fmaxf(mx, __shfl_xor(mx,2));
      mx = fmaxf(mx, __shfl_xor(mx,4));
      mx = fmaxf(mx, __shfl_xor(mx,8));
      if (lrow == 0) sT[wv][mf*16 + lk*4 + r] = mx;
    }
  __syncthreads();
  if (tid < 64){
    float t0 = fmaxf(sT[0][tid], sT[1][tid]);
    float t1 = fmaxf(sT[2][tid], sT[3][tid]);
    tout[(size_t)br*MPOS + (size_t)blockIdx.x*64 + tid] = fmaxf(t0, t1);
  }
}

// ---------------- softmax + weighted sums ----------------
__global__ void k_final(const float* __restrict__ tbuf, const int* __restrict__ nn_idx,
                        const float* __restrict__ gpx, const float* __restrict__ gpy,
                        const float* __restrict__ gpz,
                        const float* __restrict__ fT, float* __restrict__ out){
  __shared__ float sw[4][64];
  const int wv = threadIdx.x >> 6, lane = threadIdx.x & 63;
  const int m = blockIdx.x*4 + wv, b = blockIdx.y;
  const size_t pos0 = (size_t)(b*NQ + m)*KNN;
  const int half = lane >> 5, kk = lane & 31;
  float tv = tbuf[(size_t)half*MPOS + pos0 + kk];
  float mx = tv;
  #pragma unroll
  for (int s=1;s<32;s<<=1) mx = fmaxf(mx, __shfl_xor(mx, s));
  float e = __expf(tv - mx);
  float sum = e;
  #pragma unroll
  for (int s=1;s<32;s<<=1) sum += __shfl_xor(sum, s);
  sw[wv][lane] = e / sum;    // lanes 0..31: wts (a), 32..63: wts1 (b)
  __syncthreads();
  const int* nn = nn_idx + pos0;
  float ax=0, ay=0, az=0, f0=0, f1=0;
  for (int k=0;k<KNN;++k){
    int idx = nn[k];
    float wa = sw[wv][k], wb = sw[wv][32+k];
    ax = fmaf(wa, gpx[b*NPTS+idx], ax);
    ay = fmaf(wa, gpy[b*NPTS+idx], ay);
    az = fmaf(wa, gpz[b*NPTS+idx], az);
    float2 fv = *(const float2*)(fT + ((size_t)b*NPTS + idx)*CF + lane*2);
    f0 = fmaf(wb, fv.x, f0);
    f1 = fmaf(wb, fv.y, f1);
  }
  if (lane == 0){
    out[((size_t)b*131 + 0)*NQ + m] = ax;
    out[((size_t)b*131 + 1)*NQ + m] = ay;
    out[((size_t)b*131 + 2)*NQ + m] = az;
  }
  out[((size_t)b*131 + 3 + lane*2)*NQ + m] = f0;
  out[((size_t)b*131 + 4 + lane*2)*NQ + m] = f1;
}

extern "C" void kernel_launch(void* const* d_in, const int* in_sizes, int n_in,
                              void* d_out, int out_size, void* d_ws, size_t ws_size,
                              hipStream_t stream){
  const float* points1   = (const float*)d_in[0];
  const float* points2   = (const float*)d_in[1];
  const float* features1 = (const float*)d_in[2];
  const float* features2 = (const float*)d_in[3];
  const int*   randidx   = (const int*)d_in[4];
  const float* aw0 = (const float*)d_in[6];
  const float* ag0 = (const float*)d_in[8];
  const float* abe0= (const float*)d_in[9];
  const float* aw1 = (const float*)d_in[10];
  const float* ag1 = (const float*)d_in[12];
  const float* abe1= (const float*)d_in[13];
  const float* aw2 = (const float*)d_in[14];
  const float* ag2 = (const float*)d_in[16];
  const float* abe2= (const float*)d_in[17];
  const float* bw0 = (const float*)d_in[18];
  const float* bg0 = (const float*)d_in[20];
  const float* bbe0= (const float*)d_in[21];
  const float* bw1 = (const float*)d_in[22];
  const float* bg1 = (const float*)d_in[24];
  const float* bbe1= (const float*)d_in[25];
  const float* bw2 = (const float*)d_in[26];
  const float* bg2 = (const float*)d_in[28];
  const float* bbe2= (const float*)d_in[29];

  char* ws = (char*)d_ws;
  float* px   = (float*)(ws + 0);
  float* py   = (float*)(ws + 65536);
  float* pz   = (float*)(ws + 131072);
  float* fT   = (float*)(ws + 196608);                    // 8MB f32 [b][p][c]
  unsigned short* w1h = (unsigned short*)(ws + 8585216);  // 64KB (packed)
  unsigned short* w2h = (unsigned short*)(ws + 8650752);  // 128KB (packed)
  unsigned short* w1l = (unsigned short*)(ws + 8781824);  // 64KB (packed)
  unsigned short* w2l = (unsigned short*)(ws + 8847360);  // 128KB (packed)
  int*   nn   = (int*)(ws + 8978432);                     // 1MB
  float* newf = (float*)(ws + 10027008);                  // 5.24MB [pos][5]
  float* tbuf = (float*)(ws + 15269888);                  // 2MB [branch][pos]
  float* mom  = (float*)(ws + 17367040);                  // stats block
  float* y1s = mom + 20;  float* y1q = y1s + 256;
  float* y2s = y1q + 256; float* y2q = y2s + 512;

  hipMemsetAsync(mom, 0, 6224, stream);
  k_prep<<<dim3(448), 256, 0, stream>>>(points1, points2, aw1, bw1, aw2, bw2,
      px, py, pz, w1h, w1l, w2h, w2l);
  k_transpose_f<<<dim3(256,4,2), 256, 0, stream>>>(features1, features2, fT);
  k_knn<<<dim3(256,2), 1024, 0, stream>>>(px, py, pz, randidx, nn, newf);
  k_fdot<<<dim3(1024,2), 256, 0, stream>>>(fT, randidx, nn, newf);
  k_moments<<<dim3(1024), 256, 0, stream>>>(newf, mom);
  k_pass<1><<<dim3(2048,2), 256, 0, stream>>>(newf, aw0,bw0, ag0,bg0, abe0,bbe0,
      ag1,bg1, abe1,bbe1, w1h,w2h, mom, y1s,y1q,y2s,y2q);
  k_pass<2><<<dim3(2048,2), 256, 0, stream>>>(newf, aw0,bw0, ag0,bg0, abe0,bbe0,
      ag1,bg1, abe1,bbe1, w1h,w2h, mom, y1s,y1q,y2s,y2q);
  k_pass3<<<dim3(4096,2), 256, 0, stream>>>(newf, aw0,bw0, ag0,bg0, abe0,bbe0,
      ag1,bg1, abe1,bbe1, ag2,bg2, abe2,bbe2, w1h,w1l,w2h,w2l, mom,
      y1s,y1q,y2s,y2q, tbuf);
  k_final<<<dim3(1024,2), 256, 0, stream>>>(tbuf, nn, px, py, pz, fT, (float*)d_out);
}

// Round 18
// 761.347 us; speedup vs baseline: 1.1598x; 1.0309x over previous
//
#include <hip/hip_runtime.h>

#define NB 2
#define NQ 4096
#define NPTS 8192
#define KNN 32
#define CF 128
#define MPOS (NB*NQ*KNN)
#define EPSV 1e-5f

typedef __attribute__((ext_vector_type(8))) short bf16x8;
typedef __attribute__((ext_vector_type(4))) float f32x4;
typedef __attribute__((ext_vector_type(4))) unsigned int u32x4;
typedef unsigned long long u64;

__device__ __forceinline__ unsigned short f2b(float f){
  unsigned u = __float_as_uint(f);
  return (unsigned short)((u + 0x7fffu + ((u >> 16) & 1u)) >> 16);
}
__device__ __forceinline__ float b2f(unsigned short h){
  return __uint_as_float(((unsigned)h) << 16);
}
// XOR swizzle for LDS tiles with 256B rows (bf16[128] rows).
__device__ __forceinline__ unsigned swz(unsigned byte){
  return byte ^ (((byte >> 8) & 7u) << 4);
}
// fragment-packed weight index: row-tile otile=row>>4, ks=col>>5,
// lane=( (col>>3)&3 )*16 + (row&15), elem=col&7  -> coalesced 1KB/frag load.
__device__ __forceinline__ int wpack(int row, int col){
  return (((row >> 4)*4 + (col >> 5))*64 + ((col >> 3) & 3)*16 + (row & 15))*8 + (col & 7);
}

// ---------------- prep: points SoA + weights to packed bf16 hi/lo ----------
__global__ void k_prep(const float* __restrict__ p1, const float* __restrict__ p2,
                       const float* __restrict__ aw1, const float* __restrict__ bw1,
                       const float* __restrict__ aw2, const float* __restrict__ bw2,
                       float* __restrict__ px, float* __restrict__ py, float* __restrict__ pz,
                       unsigned short* __restrict__ w1h, unsigned short* __restrict__ w1l,
                       unsigned short* __restrict__ w2h, unsigned short* __restrict__ w2l){
  int t = blockIdx.x*256 + threadIdx.x;
  if (t < NB*NPTS){
    int b = t / NPTS, p = t - b*NPTS;
    const float* s = (p < NQ) ? p1 : p2;
    int pp = (p < NQ) ? p : p - NQ;
    px[t] = s[(b*3+0)*NQ + pp];
    py[t] = s[(b*3+1)*NQ + pp];
    pz[t] = s[(b*3+2)*NQ + pp];
  } else {
    int u = t - NB*NPTS;
    if (u < 32768){
      int brn = u >> 14, i = u & 16383;
      float w = brn ? bw1[i] : aw1[i];
      unsigned short hi = f2b(w);
      int pidx = brn*16384 + wpack(i >> 7, i & 127);
      w1h[pidx] = hi; w1l[pidx] = f2b(w - b2f(hi));
    } else {
      int v = u - 32768;
      if (v < 65536){
        int brn = v >> 15, i = v & 32767;
        float w = brn ? bw2[i] : aw2[i];
        unsigned short hi = f2b(w);
        int pidx = brn*32768 + wpack(i >> 7, i & 127);
        w2h[pidx] = hi; w2l[pidx] = f2b(w - b2f(hi));
      }
    }
  }
}

// ---------------- prep: feature transpose to [b][p][c] f32 ----------------
__global__ void k_transpose_f(const float* __restrict__ f1, const float* __restrict__ f2,
                              float* __restrict__ fT){
  __shared__ float tile[32][33];
  int p0 = blockIdx.x*32, c0 = blockIdx.y*32, b = blockIdx.z;
  const float* s = (p0 < NQ) ? f1 : f2;
  int pp0 = (p0 < NQ) ? p0 : p0 - NQ;
  int tx = threadIdx.x & 31, ty = threadIdx.x >> 5;
  #pragma unroll
  for (int i = 0; i < 32; i += 8)
    tile[ty+i][tx] = s[((size_t)b*CF + c0+ty+i)*NQ + pp0 + tx];
  __syncthreads();
  #pragma unroll
  for (int i = 0; i < 32; i += 8)
    fT[((size_t)b*NPTS + p0+ty+i)*CF + c0 + tx] = tile[tx][ty+i];
}

// ---------------- KNN + fused fdot: one wave per query, 16 waves/block ------
// Replicates the reference d2 formula in strict f32 (no FMA). After top-32
// selection, the same wave computes the fdot channel (gathers overlap other
// waves' scan phase; nn_idx global round-trip eliminated).
__global__ __launch_bounds__(1024,1) void k_knn(const float* __restrict__ gpx, const float* __restrict__ gpy,
        const float* __restrict__ gpz, const int* __restrict__ randidx,
        const float* __restrict__ fT,
        int* __restrict__ nn_idx, float* __restrict__ newf){
  __shared__ float4 sp[NPTS];
  __shared__ u64 sbuf[16][192];
  const int b = blockIdx.y;
  for (int i = threadIdx.x; i < NPTS; i += 1024){
    float x = gpx[b*NPTS+i], y = gpy[b*NPTS+i], z = gpz[b*NPTS+i];
    float sq = __fadd_rn(__fadd_rn(__fmul_rn(x,x), __fmul_rn(y,y)), __fmul_rn(z,z));
    sp[i] = make_float4(x, y, z, sq);
  }
  __syncthreads();
  const int wv = threadIdx.x >> 6, lane = threadIdx.x & 63;
  const int m = blockIdx.x*16 + wv;
  const int ridx = randidx[m];
  const float4 Q = sp[ridx];
  const float qx = Q.x, qy = Q.y, qz = Q.z, s1q = Q.w;
  u64* buf = sbuf[wv];

  u64 top = ~0ull;
  float thr = __builtin_inff();
  int cnt = 0;

  auto flush = [&](){
    u64 e0 = (lane       < cnt) ? buf[lane]     : ~0ull;
    u64 e1 = (lane + 64  < cnt) ? buf[lane+64]  : ~0ull;
    u64 e2 = (lane + 128 < cnt) ? buf[lane+128] : ~0ull;
    u64 e3 = (lane < KNN) ? top : ~0ull;
    #define SWP(a,b) { u64 lo_ = (a<b)?a:b; u64 hi_ = (a<b)?b:a; a=lo_; b=hi_; }
    SWP(e0,e1) SWP(e2,e3) SWP(e0,e2) SWP(e1,e3) SWP(e1,e2)
    #undef SWP
    u64 newtop = ~0ull, v = 0;
    for (int i = 0; i < KNN; ++i){
      v = e0;
      #pragma unroll
      for (int s = 1; s < 64; s <<= 1){
        u64 o = __shfl_xor(v, s);
        if (o < v) v = o;
      }
      bool win = (e0 == v);
      e0 = win ? e1 : e0; e1 = win ? e2 : e1; e2 = win ? e3 : e2;
      e3 = win ? ~0ull : e3;
      newtop = (lane == i) ? v : newtop;
    }
    top = newtop;
    unsigned k32 = (unsigned)(v >> 32);
    unsigned uu = (k32 & 0x80000000u) ? (k32 ^ 0x80000000u) : ~k32;
    thr = __uint_as_float(uu);
    cnt = 0;
  };

  for (int c = 0; c < NPTS/64; ++c){
    if (cnt > 128) flush();
    int j = c*64 + lane;
    float4 P = sp[j];
    float dot = __fadd_rn(__fadd_rn(__fmul_rn(qx,P.x), __fmul_rn(qy,P.y)), __fmul_rn(qz,P.z));
    float d   = __fsub_rn(__fadd_rn(s1q, P.w), __fmul_rn(2.0f, dot));
    bool pred = (d <= thr);
    u64 mask = __ballot(pred);
    if (mask){
      if (pred){
        int rank = __popcll(mask & ((1ull << lane) - 1ull));
        unsigned u = __float_as_uint(d);
        unsigned key = u ^ ((unsigned)((int)u >> 31) | 0x80000000u);
        buf[cnt + rank] = ((u64)key << 32) | (unsigned)j;
      }
      cnt += __popcll(mask);
    }
  }
  flush();

  if (lane < KNN){
    int idx = (int)(unsigned)(top & 0xffffffffull);
    size_t pos = (size_t)(b*NQ + m)*KNN + lane;
    nn_idx[pos] = idx;
    float4 P = sp[idx];
    float rx = P.x-qx, ry = P.y-qy, rz = P.z-qz;
    float dd = sqrtf(rx*rx + ry*ry + rz*rz);
    float* nf = newf + pos*5;
    nf[0] = rx; nf[1] = ry; nf[2] = rz; nf[3] = dd;
  }

  // fused fdot: lane=(k,half), 64 channels per lane (identical to old k_fdot)
  {
    const int k2 = lane >> 1, half = lane & 1;
    u64 tk = __shfl(top, k2);
    int nidx = (int)(unsigned)(tk & 0xffffffffull);
    const float* f1p = fT + ((size_t)b*NPTS + ridx)*CF + half*64;
    const float* gp  = fT + ((size_t)b*NPTS + nidx)*CF + half*64;
    float s = 0.0f;
    #pragma unroll
    for (int c = 0; c < 16; ++c){
      float4 a = *(const float4*)(f1p + c*4);
      float4 g = *(const float4*)(gp  + c*4);
      s += a.x*g.x + a.y*g.y + a.z*g.z + a.w*g.w;
    }
    s += __shfl_xor(s, 1);
    if (half == 0)
      newf[((size_t)(b*NQ + m)*KNN + k2)*5 + 4] = s;
  }
}

// ---------------- moments of newf (for analytic y0 stats) ----------------
__global__ void k_moments(const float* __restrict__ newf, float* __restrict__ mom){
  float v[20];
  #pragma unroll
  for (int i = 0; i < 20; ++i) v[i] = 0.0f;
  int p = blockIdx.x*256 + threadIdx.x;
  if (p < MPOS){
    const float* nf = newf + (size_t)p*5;
    float x0=nf[0], x1=nf[1], x2=nf[2], x3=nf[3], x4=nf[4];
    v[0]=x0; v[1]=x1; v[2]=x2; v[3]=x3; v[4]=x4;
    v[5]=x0*x0; v[6]=x0*x1; v[7]=x0*x2; v[8]=x0*x3; v[9]=x0*x4;
    v[10]=x1*x1; v[11]=x1*x2; v[12]=x1*x3; v[13]=x1*x4;
    v[14]=x2*x2; v[15]=x2*x3; v[16]=x2*x4;
    v[17]=x3*x3; v[18]=x3*x4; v[19]=x4*x4;
  }
  #pragma unroll
  for (int i = 0; i < 20; ++i){
    float t = v[i];
    #pragma unroll
    for (int sh = 1; sh < 64; sh <<= 1) t += __shfl_xor(t, sh);
    v[i] = t;
  }
  __shared__ float red[4][20];
  int wv = threadIdx.x >> 6, lane = threadIdx.x & 63;
  if (lane == 0){
    #pragma unroll
    for (int i = 0; i < 20; ++i) red[wv][i] = v[i];
  }
  __syncthreads();
  if (threadIdx.x < 20)
    atomicAdd(&mom[threadIdx.x],
              red[0][threadIdx.x]+red[1][threadIdx.x]+red[2][threadIdx.x]+red[3][threadIdx.x]);
}

// ---------------- stat passes: 256-thread blocks, BM=128 ----------------
// PASS 1: L0+L1, accumulate y1 sum/sumsq.  PASS 2: chain to y2, sum/sumsq.
// launch_bounds(256,3); L2 stat GEMM in FOUR 32-channel chunks (a2[4][2]).
// Weights read via fragment-packed layout -> coalesced 1KB wave loads.
template<int PASS>
__global__ __launch_bounds__(256,3) void k_pass(
    const float* __restrict__ newf,
    const float* __restrict__ aw0, const float* __restrict__ bw0,
    const float* __restrict__ ag0, const float* __restrict__ bg0,
    const float* __restrict__ abe0, const float* __restrict__ bbe0,
    const float* __restrict__ ag1, const float* __restrict__ bg1,
    const float* __restrict__ abe1, const float* __restrict__ bbe1,
    const unsigned short* __restrict__ w1b, const unsigned short* __restrict__ w2b,
    const float* __restrict__ mom,
    float* __restrict__ y1s, float* __restrict__ y1q,
    float* __restrict__ y2s, float* __restrict__ y2q)
{
  __shared__ unsigned short sX[128*128];   // x1 then x2 tile, swizzled 256B rows
  __shared__ float sF0[128*5], sFb0[128];
  __shared__ float sA1[128], sB1[128];
  __shared__ float sStat[512];

  const int tid = threadIdx.x;
  const int br = blockIdx.y;
  const float invM = 1.0f / (float)MPOS;

  if (tid < 128){
    const float* w0 = (br ? bw0 : aw0) + tid*5;
    float g  = (br ? bg0 : ag0)[tid];
    float be = (br ? bbe0: abe0)[tid];
    float w[5], m5[5];
    #pragma unroll
    for (int i=0;i<5;++i){ w[i]=w0[i]; m5[i]=mom[i]*invM; }
    float mu = 0;
    #pragma unroll
    for (int i=0;i<5;++i) mu += w[i]*m5[i];
    const int I[15] = {0,0,0,0,0,1,1,1,1,2,2,2,3,3,4};
    const int J[15] = {0,1,2,3,4,1,2,3,4,2,3,4,3,4,4};
    float e2 = 0;
    #pragma unroll
    for (int t2=0;t2<15;++t2){
      float c = (I[t2]==J[t2]) ? 1.0f : 2.0f;
      e2 += c * w[I[t2]] * w[J[t2]] * (mom[5+t2]*invM);
    }
    float var = fmaxf(e2 - mu*mu, 0.0f);
    float A = g * rsqrtf(var + EPSV);
    #pragma unroll
    for (int i=0;i<5;++i) sF0[tid*5+i] = A*w[i];
    sFb0[tid] = be - A*mu;
  }
  if (PASS >= 2 && tid < 128){
    float s = y1s[br*128+tid]*invM, q = y1q[br*128+tid]*invM;
    float var = fmaxf(q - s*s, 0.0f);
    float g = (br ? bg1 : ag1)[tid], be = (br ? bbe1 : abe1)[tid];
    float A = g*rsqrtf(var + EPSV);
    sA1[tid] = A; sB1[tid] = be - A*s;
  }
  sStat[tid] = 0.0f; sStat[256+tid] = 0.0f;

  const int p = tid >> 1, h = tid & 1;
  const size_t gp = (size_t)blockIdx.x*128 + p;
  const float* nf = newf + gp*5;
  float x0 = nf[0], x1v = nf[1], x2v = nf[2], x3v = nf[3], x4v = nf[4];
  __syncthreads();
  #pragma unroll
  for (int cc = 0; cc < 8; ++cc){
    int oc = h*64 + cc*8;
    u32x4 vv;
    #pragma unroll
    for (int jj = 0; jj < 4; ++jj){
      int o = oc + jj*2;
      float ya = sFb0[o]   + sF0[o*5+0]*x0 + sF0[o*5+1]*x1v + sF0[o*5+2]*x2v + sF0[o*5+3]*x3v + sF0[o*5+4]*x4v;
      float yb = sFb0[o+1] + sF0[(o+1)*5+0]*x0 + sF0[(o+1)*5+1]*x1v + sF0[(o+1)*5+2]*x2v + sF0[(o+1)*5+3]*x3v + sF0[(o+1)*5+4]*x4v;
      vv[jj] = (unsigned)f2b(fmaxf(ya,0.0f)) | ((unsigned)f2b(fmaxf(yb,0.0f)) << 16);
    }
    *(u32x4*)((char*)sX + swz((unsigned)(p*256 + oc*2))) = vv;
  }
  __syncthreads();

  const int wv = tid >> 6, lane = tid & 63;
  const int mb = wv >> 1, nb = wv & 1;
  const int lrow = lane & 15, lk = lane >> 4;
  const unsigned short* w1g = w1b + br*16384;
  f32x4 zf = {0.0f, 0.0f, 0.0f, 0.0f};
  f32x4 acc[4][4];
  #pragma unroll
  for (int i=0;i<4;++i)
    #pragma unroll
    for (int j=0;j<4;++j) acc[i][j] = zf;

  #pragma unroll
  for (int ks = 0; ks < 4; ++ks){
    bf16x8 af[4], bfr[4];
    #pragma unroll
    for (int mf = 0; mf < 4; ++mf){
      int row = mb*64 + mf*16 + lrow;
      af[mf] = *(bf16x8*)((char*)sX + swz((unsigned)(row*256 + ks*64 + lk*16)));
    }
    #pragma unroll
    for (int nf2 = 0; nf2 < 4; ++nf2){
      int otile = nb*4 + nf2;
      bfr[nf2] = *(const bf16x8*)(w1g + ((otile*4 + ks)*64 + lane)*8);
    }
    #pragma unroll
    for (int mf = 0; mf < 4; ++mf)
      #pragma unroll
      for (int nf2 = 0; nf2 < 4; ++nf2)
        acc[mf][nf2] = __builtin_amdgcn_mfma_f32_16x16x32_bf16(af[mf], bfr[nf2], acc[mf][nf2], 0, 0, 0);
  }

  if (PASS == 1){
    #pragma unroll
    for (int nf2 = 0; nf2 < 4; ++nf2){
      float s = 0, q = 0;
      #pragma unroll
      for (int mf=0;mf<4;++mf)
        #pragma unroll
        for (int r=0;r<4;++r){ float v2 = acc[mf][nf2][r]; s += v2; q += v2*v2; }
      s += __shfl_xor(s,16); s += __shfl_xor(s,32);
      q += __shfl_xor(q,16); q += __shfl_xor(q,32);
      if (lane < 16){
        int o = nb*64 + nf2*16 + lrow;
        atomicAdd(&sStat[o], s);
        atomicAdd(&sStat[256+o], q);
      }
    }
    __syncthreads();
    if (tid < 128){
      atomicAdd(&y1s[br*128 + tid], sStat[tid]);
      atomicAdd(&y1q[br*128 + tid], sStat[256+tid]);
    }
    return;
  }

  __syncthreads();   // all waves done reading sX(x1)
  #pragma unroll
  for (int nf2 = 0; nf2 < 4; ++nf2){
    int o = nb*64 + nf2*16 + lrow;
    float A = sA1[o], Bc = sB1[o];
    #pragma unroll
    for (int mf = 0; mf < 4; ++mf)
      #pragma unroll
      for (int r = 0; r < 4; ++r){
        float xv = fmaxf(fmaf(A, acc[mf][nf2][r], Bc), 0.0f);
        int mm = mb*64 + mf*16 + lk*4 + r;
        *(unsigned short*)((char*)sX + swz((unsigned)(mm*256 + o*2))) = f2b(xv);
      }
  }
  __syncthreads();

  // L2 stat GEMM in FOUR 32-channel chunks (a2[4][2] keeps reg demand low)
  const unsigned short* w2 = w2b + br*32768;
  #pragma unroll
  for (int nh = 0; nh < 4; ++nh){
    f32x4 a2[4][2];
    #pragma unroll
    for (int i=0;i<4;++i)
      #pragma unroll
      for (int j=0;j<2;++j) a2[i][j] = zf;
    #pragma unroll
    for (int ks = 0; ks < 4; ++ks){
      bf16x8 af[4];
      #pragma unroll
      for (int mf = 0; mf < 4; ++mf){
        int row = mb*64 + mf*16 + lrow;
        af[mf] = *(bf16x8*)((char*)sX + swz((unsigned)(row*256 + ks*64 + lk*16)));
      }
      bf16x8 bw2f[2];
      #pragma unroll
      for (int nf2 = 0; nf2 < 2; ++nf2){
        int otile = nb*8 + nh*2 + nf2;
        bw2f[nf2] = *(const bf16x8*)(w2 + ((otile*4 + ks)*64 + lane)*8);
      }
      #pragma unroll
      for (int mf = 0; mf < 4; ++mf)
        #pragma unroll
        for (int nf2 = 0; nf2 < 2; ++nf2)
          a2[mf][nf2] = __builtin_amdgcn_mfma_f32_16x16x32_bf16(af[mf], bw2f[nf2], a2[mf][nf2], 0, 0, 0);
    }
    #pragma unroll
    for (int nf2 = 0; nf2 < 2; ++nf2){
      float s = 0, q = 0;
      #pragma unroll
      for (int mf=0;mf<4;++mf)
        #pragma unroll
        for (int r=0;r<4;++r){ float v2 = a2[mf][nf2][r]; s += v2; q += v2*v2; }
      s += __shfl_xor(s,16); s += __shfl_xor(s,32);
      q += __shfl_xor(q,16); q += __shfl_xor(q,32);
      if (lane < 16){
        int o = nb*128 + nh*32 + nf2*16 + lrow;
        atomicAdd(&sStat[o], s);
        atomicAdd(&sStat[256+o], q);
      }
    }
  }
  __syncthreads();
  atomicAdd(&y2s[br*256 + tid], sStat[tid]);
  atomicAdd(&y2q[br*256 + tid], sStat[256+tid]);
}

// ---------------- final pass: split-bf16, 256-thread blocks, BM=64 ----------
// launch_bounds(256,3): verified optimum (R9/R11/R13). Packed-weight loads.
__global__ __launch_bounds__(256,3) void k_pass3(
    const float* __restrict__ newf,
    const float* __restrict__ aw0, const float* __restrict__ bw0,
    const float* __restrict__ ag0, const float* __restrict__ bg0,
    const float* __restrict__ abe0, const float* __restrict__ bbe0,
    const float* __restrict__ ag1, const float* __restrict__ bg1,
    const float* __restrict__ abe1, const float* __restrict__ bbe1,
    const float* __restrict__ ag2, const float* __restrict__ bg2,
    const float* __restrict__ abe2, const float* __restrict__ bbe2,
    const unsigned short* __restrict__ w1h, const unsigned short* __restrict__ w1l,
    const unsigned short* __restrict__ w2h, const unsigned short* __restrict__ w2l,
    const float* __restrict__ mom,
    const float* __restrict__ y1s, const float* __restrict__ y1q,
    const float* __restrict__ y2s, const float* __restrict__ y2q,
    float* __restrict__ tout)
{
  __shared__ unsigned short sXh[64*128], sXl[64*128];
  __shared__ float sF0[128*5], sFb0[128];
  __shared__ float sA1[128], sB1[128];
  __shared__ float sA2[256], sB2[256];
  __shared__ float sT[4][64];

  const int tid = threadIdx.x;
  const int br = blockIdx.y;
  const float invM = 1.0f / (float)MPOS;

  if (tid < 128){
    const float* w0 = (br ? bw0 : aw0) + tid*5;
    float g  = (br ? bg0 : ag0)[tid];
    float be = (br ? bbe0: abe0)[tid];
    float w[5], m5[5];
    #pragma unroll
    for (int i=0;i<5;++i){ w[i]=w0[i]; m5[i]=mom[i]*invM; }
    float mu = 0;
    #pragma unroll
    for (int i=0;i<5;++i) mu += w[i]*m5[i];
    const int I[15] = {0,0,0,0,0,1,1,1,1,2,2,2,3,3,4};
    const int J[15] = {0,1,2,3,4,1,2,3,4,2,3,4,3,4,4};
    float e2 = 0;
    #pragma unroll
    for (int t2=0;t2<15;++t2){
      float c = (I[t2]==J[t2]) ? 1.0f : 2.0f;
      e2 += c * w[I[t2]] * w[J[t2]] * (mom[5+t2]*invM);
    }
    float var = fmaxf(e2 - mu*mu, 0.0f);
    float A = g * rsqrtf(var + EPSV);
    #pragma unroll
    for (int i=0;i<5;++i) sF0[tid*5+i] = A*w[i];
    sFb0[tid] = be - A*mu;

    float s1 = y1s[br*128+tid]*invM, q1 = y1q[br*128+tid]*invM;
    float var1 = fmaxf(q1 - s1*s1, 0.0f);
    float g1 = (br ? bg1 : ag1)[tid], be1 = (br ? bbe1 : abe1)[tid];
    float A1 = g1*rsqrtf(var1 + EPSV);
    sA1[tid] = A1; sB1[tid] = be1 - A1*s1;
  }
  {
    int c2 = tid;           // 256 threads cover 256 channels
    float s = y2s[br*256+c2]*invM, q = y2q[br*256+c2]*invM;
    float var = fmaxf(q - s*s, 0.0f);
    float g = (br ? bg2 : ag2)[c2], be = (br ? bbe2 : abe2)[c2];
    float A = g*rsqrtf(var + EPSV);
    sA2[c2] = A; sB2[c2] = be - A*s;
  }

  // x1 tile: 4 threads per position, 32 channels each; split hi/lo
  const int p = tid >> 2, h = tid & 3;
  const size_t gp = (size_t)blockIdx.x*64 + p;
  const float* nf = newf + gp*5;
  float x0 = nf[0], x1v = nf[1], x2v = nf[2], x3v = nf[3], x4v = nf[4];
  __syncthreads();
  #pragma unroll
  for (int cc = 0; cc < 4; ++cc){
    int oc = h*32 + cc*8;
    u32x4 vh, vl;
    #pragma unroll
    for (int jj = 0; jj < 4; ++jj){
      int o = oc + jj*2;
      float ya = sFb0[o]   + sF0[o*5+0]*x0 + sF0[o*5+1]*x1v + sF0[o*5+2]*x2v + sF0[o*5+3]*x3v + sF0[o*5+4]*x4v;
      float yb = sFb0[o+1] + sF0[(o+1)*5+0]*x0 + sF0[(o+1)*5+1]*x1v + sF0[(o+1)*5+2]*x2v + sF0[(o+1)*5+3]*x3v + sF0[(o+1)*5+4]*x4v;
      ya = fmaxf(ya, 0.0f); yb = fmaxf(yb, 0.0f);
      unsigned short ha = f2b(ya), hb = f2b(yb);
      unsigned short la = f2b(ya - b2f(ha)), lb = f2b(yb - b2f(hb));
      vh[jj] = (unsigned)ha | ((unsigned)hb << 16);
      vl[jj] = (unsigned)la | ((unsigned)lb << 16);
    }
    unsigned off = swz((unsigned)(p*256 + oc*2));
    *(u32x4*)((char*)sXh + off) = vh;
    *(u32x4*)((char*)sXl + off) = vl;
  }
  __syncthreads();

  // L1: y1[64x128] = x1 * W1^T; wave w owns 32 channels, all 64 rows (mf4)
  const int wv = tid >> 6, lane = tid & 63;
  const int lrow = lane & 15, lk = lane >> 4;
  const unsigned short* w1hb = w1h + br*16384;
  const unsigned short* w1lb = w1l + br*16384;
  f32x4 zf = {0.0f, 0.0f, 0.0f, 0.0f};
  f32x4 acc[4][2];
  #pragma unroll
  for (int i=0;i<4;++i)
    #pragma unroll
    for (int j=0;j<2;++j) acc[i][j] = zf;

  #pragma unroll
  for (int ks = 0; ks < 4; ++ks){
    bf16x8 ah[4], al[4], bh[2], bl[2];
    #pragma unroll
    for (int mf = 0; mf < 4; ++mf){
      unsigned off = swz((unsigned)((mf*16 + lrow)*256 + ks*64 + lk*16));
      ah[mf] = *(bf16x8*)((char*)sXh + off);
      al[mf] = *(bf16x8*)((char*)sXl + off);
    }
    #pragma unroll
    for (int nf2 = 0; nf2 < 2; ++nf2){
      int otile = wv*2 + nf2;
      bh[nf2] = *(const bf16x8*)(w1hb + ((otile*4 + ks)*64 + lane)*8);
      bl[nf2] = *(const bf16x8*)(w1lb + ((otile*4 + ks)*64 + lane)*8);
    }
    #pragma unroll
    for (int mf = 0; mf < 4; ++mf)
      #pragma unroll
      for (int nf2 = 0; nf2 < 2; ++nf2){
        acc[mf][nf2] = __builtin_amdgcn_mfma_f32_16x16x32_bf16(ah[mf], bh[nf2], acc[mf][nf2], 0, 0, 0);
        acc[mf][nf2] = __builtin_amdgcn_mfma_f32_16x16x32_bf16(ah[mf], bl[nf2], acc[mf][nf2], 0, 0, 0);
        acc[mf][nf2] = __builtin_amdgcn_mfma_f32_16x16x32_bf16(al[mf], bh[nf2], acc[mf][nf2], 0, 0, 0);
      }
  }

  __syncthreads();   // all waves done reading x1 tiles
  // x2 = relu(bn1(y1)) -> sXh/sXl (C/D: col=lane&15, row=(lane>>4)*4+r)
  #pragma unroll
  for (int nf2 = 0; nf2 < 2; ++nf2){
    int o = wv*32 + nf2*16 + lrow;
    float A = sA1[o], Bc = sB1[o];
    #pragma unroll
    for (int mf = 0; mf < 4; ++mf)
      #pragma unroll
      for (int r = 0; r < 4; ++r){
        float xv = fmaxf(fmaf(A, acc[mf][nf2][r], Bc), 0.0f);
        int mm = mf*16 + lk*4 + r;
        unsigned short hi = f2b(xv);
        unsigned short lo = f2b(xv - b2f(hi));
        unsigned off = swz((unsigned)(mm*256 + o*2));
        *(unsigned short*)((char*)sXh + off) = hi;
        *(unsigned short*)((char*)sXl + off) = lo;
      }
  }
  __syncthreads();

  // L2: y2[64x256] = x2 * W2^T; wave w owns channels w*64..w*64+63 (2 chunks)
  const unsigned short* w2hb = w2h + br*32768;
  const unsigned short* w2lb = w2l + br*32768;
  float mxv[4][4];
  #pragma unroll
  for (int mf=0;mf<4;++mf)
    #pragma unroll
    for (int r=0;r<4;++r) mxv[mf][r] = 0.0f;   // relu >= 0

  #pragma unroll
  for (int nh = 0; nh < 2; ++nh){
    f32x4 a2[4][2];
    #pragma unroll
    for (int i=0;i<4;++i)
      #pragma unroll
      for (int j=0;j<2;++j) a2[i][j] = zf;
    #pragma unroll
    for (int ks = 0; ks < 4; ++ks){
      bf16x8 ah[4], al[4], bh[2], bl[2];
      #pragma unroll
      for (int mf = 0; mf < 4; ++mf){
        unsigned off = swz((unsigned)((mf*16 + lrow)*256 + ks*64 + lk*16));
        ah[mf] = *(bf16x8*)((char*)sXh + off);
        al[mf] = *(bf16x8*)((char*)sXl + off);
      }
      #pragma unroll
      for (int nf2 = 0; nf2 < 2; ++nf2){
        int otile = wv*4 + nh*2 + nf2;
        bh[nf2] = *(const bf16x8*)(w2hb + ((otile*4 + ks)*64 + lane)*8);
        bl[nf2] = *(const bf16x8*)(w2lb + ((otile*4 + ks)*64 + lane)*8);
      }
      #pragma unroll
      for (int mf = 0; mf < 4; ++mf)
        #pragma unroll
        for (int nf2 = 0; nf2 < 2; ++nf2){
          a2[mf][nf2] = __builtin_amdgcn_mfma_f32_16x16x32_bf16(ah[mf], bh[nf2], a2[mf][nf2], 0, 0, 0);
          a2[mf][nf2] = __builtin_amdgcn_mfma_f32_16x16x32_bf16(ah[mf], bl[nf2], a2[mf][nf2], 0, 0, 0);
          a2[mf][nf2] = __builtin_amdgcn_mfma_f32_16x16x32_bf16(al[mf], bh[nf2], a2[mf][nf2], 0, 0, 0);
        }
    }
    // bn2 + relu + running channel-max for this chunk
    #pragma unroll
    for (int mf = 0; mf < 4; ++mf)
      #pragma unroll
      for (int r = 0; r < 4; ++r){
        #pragma unroll
        for (int nf2 = 0; nf2 < 2; ++nf2){
          int o = wv*64 + nh*32 + nf2*16 + lrow;
          mxv[mf][r] = fmaxf(mxv[mf][r], fmaxf(fmaf(sA2[o], a2[mf][nf2][r], sB2[o]), 0.0f));
        }
      }
  }

  // per-wave max over its 64 channels -> sT[w][row]
  #pragma unroll
  for (int mf = 0; mf < 4; ++mf)
    #pragma unroll
    for (int r = 0; r < 4; ++r){
      float mx = mxv[mf][r];
      mx = fmaxf(mx, __shfl_xor(mx,1));
      mx = fmaxf(mx, __shfl_xor(mx,2));
      mx = fmaxf(mx, __shfl_xor(mx,4));
      mx = fmaxf(mx, __shfl_xor(mx,8));
      if (lrow == 0) sT[wv][mf*16 + lk*4 + r] = mx;
    }
  __syncthreads();
  if (tid < 64){
    float t0 = fmaxf(sT[0][tid], sT[1][tid]);
    float t1 = fmaxf(sT[2][tid], sT[3][tid]);
    tout[(size_t)br*MPOS + (size_t)blockIdx.x*64 + tid] = fmaxf(t0, t1);
  }
}

// ---------------- softmax + weighted sums ----------------
__global__ void k_final(const float* __restrict__ tbuf, const int* __restrict__ nn_idx,
                        const float* __restrict__ gpx, const float* __restrict__ gpy,
                        const float* __restrict__ gpz,
                        const float* __restrict__ fT, float* __restrict__ out){
  __shared__ float sw[4][64];
  const int wv = threadIdx.x >> 6, lane = threadIdx.x & 63;
  const int m = blockIdx.x*4 + wv, b = blockIdx.y;
  const size_t pos0 = (size_t)(b*NQ + m)*KNN;
  const int half = lane >> 5, kk = lane & 31;
  float tv = tbuf[(size_t)half*MPOS + pos0 + kk];
  float mx = tv;
  #pragma unroll
  for (int s=1;s<32;s<<=1) mx = fmaxf(mx, __shfl_xor(mx, s));
  float e = __expf(tv - mx);
  float sum = e;
  #pragma unroll
  for (int s=1;s<32;s<<=1) sum += __shfl_xor(sum, s);
  sw[wv][lane] = e / sum;    // lanes 0..31: wts (a), 32..63: wts1 (b)
  __syncthreads();
  const int* nn = nn_idx + pos0;
  float ax=0, ay=0, az=0, f0=0, f1=0;
  for (int k=0;k<KNN;++k){
    int idx = nn[k];
    float wa = sw[wv][k], wb = sw[wv][32+k];
    ax = fmaf(wa, gpx[b*NPTS+idx], ax);
    ay = fmaf(wa, gpy[b*NPTS+idx], ay);
    az = fmaf(wa, gpz[b*NPTS+idx], az);
    float2 fv = *(const float2*)(fT + ((size_t)b*NPTS + idx)*CF + lane*2);
    f0 = fmaf(wb, fv.x, f0);
    f1 = fmaf(wb, fv.y, f1);
  }
  if (lane == 0){
    out[((size_t)b*131 + 0)*NQ + m] = ax;
    out[((size_t)b*131 + 1)*NQ + m] = ay;
    out[((size_t)b*131 + 2)*NQ + m] = az;
  }
  out[((size_t)b*131 + 3 + lane*2)*NQ + m] = f0;
  out[((size_t)b*131 + 4 + lane*2)*NQ + m] = f1;
}

extern "C" void kernel_launch(void* const* d_in, const int* in_sizes, int n_in,
                              void* d_out, int out_size, void* d_ws, size_t ws_size,
                              hipStream_t stream){
  const float* points1   = (const float*)d_in[0];
  const float* points2   = (const float*)d_in[1];
  const float* features1 = (const float*)d_in[2];
  const float* features2 = (const float*)d_in[3];
  const int*   randidx   = (const int*)d_in[4];
  const float* aw0 = (const float*)d_in[6];
  const float* ag0 = (const float*)d_in[8];
  const float* abe0= (const float*)d_in[9];
  const float* aw1 = (const float*)d_in[10];
  const float* ag1 = (const float*)d_in[12];
  const float* abe1= (const float*)d_in[13];
  const float* aw2 = (const float*)d_in[14];
  const float* ag2 = (const float*)d_in[16];
  const float* abe2= (const float*)d_in[17];
  const float* bw0 = (const float*)d_in[18];
  const float* bg0 = (const float*)d_in[20];
  const float* bbe0= (const float*)d_in[21];
  const float* bw1 = (const float*)d_in[22];
  const float* bg1 = (const float*)d_in[24];
  const float* bbe1= (const float*)d_in[25];
  const float* bw2 = (const float*)d_in[26];
  const float* bg2 = (const float*)d_in[28];
  const float* bbe2= (const float*)d_in[29];

  char* ws = (char*)d_ws;
  float* px   = (float*)(ws + 0);
  float* py   = (float*)(ws + 65536);
  float* pz   = (float*)(ws + 131072);
  float* fT   = (float*)(ws + 196608);                    // 8MB f32 [b][p][c]
  unsigned short* w1h = (unsigned short*)(ws + 8585216);  // 64KB (packed)
  unsigned short* w2h = (unsigned short*)(ws + 8650752);  // 128KB (packed)
  unsigned short* w1l = (unsigned short*)(ws + 8781824);  // 64KB (packed)
  unsigned short* w2l = (unsigned short*)(ws + 8847360);  // 128KB (packed)
  int*   nn   = (int*)(ws + 8978432);                     // 1MB
  float* newf = (float*)(ws + 10027008);                  // 5.24MB [pos][5]
  float* tbuf = (float*)(ws + 15269888);                  // 2MB [branch][pos]
  float* mom  = (float*)(ws + 17367040);                  // stats block
  float* y1s = mom + 20;  float* y1q = y1s + 256;
  float* y2s = y1q + 256; float* y2q = y2s + 512;

  hipMemsetAsync(mom, 0, 6224, stream);
  k_prep<<<dim3(448), 256, 0, stream>>>(points1, points2, aw1, bw1, aw2, bw2,
      px, py, pz, w1h, w1l, w2h, w2l);
  k_transpose_f<<<dim3(256,4,2), 256, 0, stream>>>(features1, features2, fT);
  k_knn<<<dim3(256,2), 1024, 0, stream>>>(px, py, pz, randidx, fT, nn, newf);
  k_moments<<<dim3(1024), 256, 0, stream>>>(newf, mom);
  k_pass<1><<<dim3(2048,2), 256, 0, stream>>>(newf, aw0,bw0, ag0,bg0, abe0,bbe0,
      ag1,bg1, abe1,bbe1, w1h,w2h, mom, y1s,y1q,y2s,y2q);
  k_pass<2><<<dim3(2048,2), 256, 0, stream>>>(newf, aw0,bw0, ag0,bg0, abe0,bbe0,
      ag1,bg1, abe1,bbe1, w1h,w2h, mom, y1s,y1q,y2s,y2q);
  k_pass3<<<dim3(4096,2), 256, 0, stream>>>(newf, aw0,bw0, ag0,bg0, abe0,bbe0,
      ag1,bg1, abe1,bbe1, ag2,bg2, abe2,bbe2, w1h,w1l,w2h,w2l, mom,
      y1s,y1q,y2s,y2q, tbuf);
  k_final<<<dim3(1024,2), 256, 0, stream>>>(tbuf, nn, px, py, pz, fT, (float*)d_out);
}

// Round 19
// 756.431 us; speedup vs baseline: 1.1673x; 1.0065x over previous
//
#include <hip/hip_runtime.h>

#define NB 2
#define NQ 4096
#define NPTS 8192
#define KNN 32
#define CF 128
#define MPOS (NB*NQ*KNN)
#define EPSV 1e-5f

typedef __attribute__((ext_vector_type(8))) short bf16x8;
typedef __attribute__((ext_vector_type(4))) float f32x4;
typedef __attribute__((ext_vector_type(4))) unsigned int u32x4;
typedef unsigned long long u64;

__device__ __forceinline__ unsigned short f2b(float f){
  unsigned u = __float_as_uint(f);
  return (unsigned short)((u + 0x7fffu + ((u >> 16) & 1u)) >> 16);
}
__device__ __forceinline__ float b2f(unsigned short h){
  return __uint_as_float(((unsigned)h) << 16);
}
// XOR swizzle for LDS tiles with 256B rows (bf16[128] rows).
__device__ __forceinline__ unsigned swz(unsigned byte){
  return byte ^ (((byte >> 8) & 7u) << 4);
}
// fragment-packed weight index: row-tile otile=row>>4, ks=col>>5,
// lane=( (col>>3)&3 )*16 + (row&15), elem=col&7  -> coalesced 1KB/frag load.
__device__ __forceinline__ int wpack(int row, int col){
  return (((row >> 4)*4 + (col >> 5))*64 + ((col >> 3) & 3)*16 + (row & 15))*8 + (col & 7);
}

// ---------------- prep: points SoA + weights to packed bf16 hi/lo ----------
__global__ void k_prep(const float* __restrict__ p1, const float* __restrict__ p2,
                       const float* __restrict__ aw1, const float* __restrict__ bw1,
                       const float* __restrict__ aw2, const float* __restrict__ bw2,
                       float* __restrict__ px, float* __restrict__ py, float* __restrict__ pz,
                       unsigned short* __restrict__ w1h, unsigned short* __restrict__ w1l,
                       unsigned short* __restrict__ w2h, unsigned short* __restrict__ w2l){
  int t = blockIdx.x*256 + threadIdx.x;
  if (t < NB*NPTS){
    int b = t / NPTS, p = t - b*NPTS;
    const float* s = (p < NQ) ? p1 : p2;
    int pp = (p < NQ) ? p : p - NQ;
    px[t] = s[(b*3+0)*NQ + pp];
    py[t] = s[(b*3+1)*NQ + pp];
    pz[t] = s[(b*3+2)*NQ + pp];
  } else {
    int u = t - NB*NPTS;
    if (u < 32768){
      int brn = u >> 14, i = u & 16383;
      float w = brn ? bw1[i] : aw1[i];
      unsigned short hi = f2b(w);
      int pidx = brn*16384 + wpack(i >> 7, i & 127);
      w1h[pidx] = hi; w1l[pidx] = f2b(w - b2f(hi));
    } else {
      int v = u - 32768;
      if (v < 65536){
        int brn = v >> 15, i = v & 32767;
        float w = brn ? bw2[i] : aw2[i];
        unsigned short hi = f2b(w);
        int pidx = brn*32768 + wpack(i >> 7, i & 127);
        w2h[pidx] = hi; w2l[pidx] = f2b(w - b2f(hi));
      }
    }
  }
}

// ---------------- prep: feature transpose to [b][p][c] f32 ----------------
__global__ void k_transpose_f(const float* __restrict__ f1, const float* __restrict__ f2,
                              float* __restrict__ fT){
  __shared__ float tile[32][33];
  int p0 = blockIdx.x*32, c0 = blockIdx.y*32, b = blockIdx.z;
  const float* s = (p0 < NQ) ? f1 : f2;
  int pp0 = (p0 < NQ) ? p0 : p0 - NQ;
  int tx = threadIdx.x & 31, ty = threadIdx.x >> 5;
  #pragma unroll
  for (int i = 0; i < 32; i += 8)
    tile[ty+i][tx] = s[((size_t)b*CF + c0+ty+i)*NQ + pp0 + tx];
  __syncthreads();
  #pragma unroll
  for (int i = 0; i < 32; i += 8)
    fT[((size_t)b*NPTS + p0+ty+i)*CF + c0 + tx] = tile[tx][ty+i];
}

// ------ KNN + fused fdot + fused moments: one wave per query, 16 waves ------
// Replicates the reference d2 formula in strict f32 (no FMA). After top-32
// selection, the same wave computes the fdot channel and accumulates the
// 5x5 moment sums (k_moments eliminated; sbuf reused for block reduce).
__global__ __launch_bounds__(1024,1) void k_knn(const float* __restrict__ gpx, const float* __restrict__ gpy,
        const float* __restrict__ gpz, const int* __restrict__ randidx,
        const float* __restrict__ fT,
        int* __restrict__ nn_idx, float* __restrict__ newf,
        float* __restrict__ mom){
  __shared__ float4 sp[NPTS];
  __shared__ u64 sbuf[16][192];
  const int b = blockIdx.y;
  for (int i = threadIdx.x; i < NPTS; i += 1024){
    float x = gpx[b*NPTS+i], y = gpy[b*NPTS+i], z = gpz[b*NPTS+i];
    float sq = __fadd_rn(__fadd_rn(__fmul_rn(x,x), __fmul_rn(y,y)), __fmul_rn(z,z));
    sp[i] = make_float4(x, y, z, sq);
  }
  __syncthreads();
  const int wv = threadIdx.x >> 6, lane = threadIdx.x & 63;
  const int m = blockIdx.x*16 + wv;
  const int ridx = randidx[m];
  const float4 Q = sp[ridx];
  const float qx = Q.x, qy = Q.y, qz = Q.z, s1q = Q.w;
  u64* buf = sbuf[wv];

  u64 top = ~0ull;
  float thr = __builtin_inff();
  int cnt = 0;

  auto flush = [&](){
    u64 e0 = (lane       < cnt) ? buf[lane]     : ~0ull;
    u64 e1 = (lane + 64  < cnt) ? buf[lane+64]  : ~0ull;
    u64 e2 = (lane + 128 < cnt) ? buf[lane+128] : ~0ull;
    u64 e3 = (lane < KNN) ? top : ~0ull;
    #define SWP(a,b) { u64 lo_ = (a<b)?a:b; u64 hi_ = (a<b)?b:a; a=lo_; b=hi_; }
    SWP(e0,e1) SWP(e2,e3) SWP(e0,e2) SWP(e1,e3) SWP(e1,e2)
    #undef SWP
    u64 newtop = ~0ull, v = 0;
    for (int i = 0; i < KNN; ++i){
      v = e0;
      #pragma unroll
      for (int s = 1; s < 64; s <<= 1){
        u64 o = __shfl_xor(v, s);
        if (o < v) v = o;
      }
      bool win = (e0 == v);
      e0 = win ? e1 : e0; e1 = win ? e2 : e1; e2 = win ? e3 : e2;
      e3 = win ? ~0ull : e3;
      newtop = (lane == i) ? v : newtop;
    }
    top = newtop;
    unsigned k32 = (unsigned)(v >> 32);
    unsigned uu = (k32 & 0x80000000u) ? (k32 ^ 0x80000000u) : ~k32;
    thr = __uint_as_float(uu);
    cnt = 0;
  };

  for (int c = 0; c < NPTS/64; ++c){
    if (cnt > 128) flush();
    int j = c*64 + lane;
    float4 P = sp[j];
    float dot = __fadd_rn(__fadd_rn(__fmul_rn(qx,P.x), __fmul_rn(qy,P.y)), __fmul_rn(qz,P.z));
    float d   = __fsub_rn(__fadd_rn(s1q, P.w), __fmul_rn(2.0f, dot));
    bool pred = (d <= thr);
    u64 mask = __ballot(pred);
    if (mask){
      if (pred){
        int rank = __popcll(mask & ((1ull << lane) - 1ull));
        unsigned u = __float_as_uint(d);
        unsigned key = u ^ ((unsigned)((int)u >> 31) | 0x80000000u);
        buf[cnt + rank] = ((u64)key << 32) | (unsigned)j;
      }
      cnt += __popcll(mask);
    }
  }
  flush();

  const bool valid = (lane < KNN);
  int idxn = valid ? (int)(unsigned)(top & 0xffffffffull) : 0;
  float4 Pn = sp[idxn];
  float rx = Pn.x-qx, ry = Pn.y-qy, rz = Pn.z-qz;
  float dd = sqrtf(rx*rx + ry*ry + rz*rz);
  if (valid){
    size_t pos = (size_t)(b*NQ + m)*KNN + lane;
    nn_idx[pos] = idxn;
    float* nf = newf + pos*5;
    nf[0] = rx; nf[1] = ry; nf[2] = rz; nf[3] = dd;
  }

  // fused fdot: lane=(k,half), 64 channels per lane (identical to old k_fdot)
  float sful;
  {
    const int k2 = lane >> 1, half = lane & 1;
    u64 tk = __shfl(top, k2);
    int nidx = (int)(unsigned)(tk & 0xffffffffull);
    const float* f1p = fT + ((size_t)b*NPTS + ridx)*CF + half*64;
    const float* gp  = fT + ((size_t)b*NPTS + nidx)*CF + half*64;
    float s = 0.0f;
    #pragma unroll
    for (int c = 0; c < 16; ++c){
      float4 a = *(const float4*)(f1p + c*4);
      float4 g = *(const float4*)(gp  + c*4);
      s += a.x*g.x + a.y*g.y + a.z*g.z + a.w*g.w;
    }
    s += __shfl_xor(s, 1);
    sful = s;
    if (half == 0)
      newf[((size_t)(b*NQ + m)*KNN + k2)*5 + 4] = s;
  }

  // fused moments: lane<32 holds x0..x3 of pos (m,lane); x4 lives on lane 2*lane
  {
    float x4 = __shfl(sful, (lane & 31)*2);
    float x0 = valid ? rx : 0.0f, x1 = valid ? ry : 0.0f;
    float x2 = valid ? rz : 0.0f, x3 = valid ? dd : 0.0f;
    x4 = valid ? x4 : 0.0f;
    float v[20];
    v[0]=x0; v[1]=x1; v[2]=x2; v[3]=x3; v[4]=x4;
    v[5]=x0*x0; v[6]=x0*x1; v[7]=x0*x2; v[8]=x0*x3; v[9]=x0*x4;
    v[10]=x1*x1; v[11]=x1*x2; v[12]=x1*x3; v[13]=x1*x4;
    v[14]=x2*x2; v[15]=x2*x3; v[16]=x2*x4;
    v[17]=x3*x3; v[18]=x3*x4; v[19]=x4*x4;
    #pragma unroll
    for (int i = 0; i < 20; ++i){
      float t = v[i];
      #pragma unroll
      for (int sh = 1; sh < 64; sh <<= 1) t += __shfl_xor(t, sh);
      v[i] = t;
    }
    float* wred = (float*)sbuf[wv];   // sbuf dead after final flush
    if (lane == 0){
      #pragma unroll
      for (int i = 0; i < 20; ++i) wred[i] = v[i];
    }
    __syncthreads();
    if (threadIdx.x < 20){
      float acc = 0.0f;
      #pragma unroll
      for (int w2 = 0; w2 < 16; ++w2) acc += ((float*)sbuf[w2])[threadIdx.x];
      atomicAdd(&mom[threadIdx.x], acc);
    }
  }
}

// ---------------- stat passes: 256-thread blocks, BM=128 ----------------
// PASS 1: L0+L1, accumulate y1 sum/sumsq.  PASS 2: chain to y2, sum/sumsq.
// launch_bounds(256,3); L2 stat GEMM in FOUR 32-channel chunks (a2[4][2]).
// Weights read via fragment-packed layout -> coalesced 1KB wave loads.
template<int PASS>
__global__ __launch_bounds__(256,3) void k_pass(
    const float* __restrict__ newf,
    const float* __restrict__ aw0, const float* __restrict__ bw0,
    const float* __restrict__ ag0, const float* __restrict__ bg0,
    const float* __restrict__ abe0, const float* __restrict__ bbe0,
    const float* __restrict__ ag1, const float* __restrict__ bg1,
    const float* __restrict__ abe1, const float* __restrict__ bbe1,
    const unsigned short* __restrict__ w1b, const unsigned short* __restrict__ w2b,
    const float* __restrict__ mom,
    float* __restrict__ y1s, float* __restrict__ y1q,
    float* __restrict__ y2s, float* __restrict__ y2q)
{
  __shared__ unsigned short sX[128*128];   // x1 then x2 tile, swizzled 256B rows
  __shared__ float sF0[128*5], sFb0[128];
  __shared__ float sA1[128], sB1[128];
  __shared__ float sStat[512];

  const int tid = threadIdx.x;
  const int br = blockIdx.y;
  const float invM = 1.0f / (float)MPOS;

  if (tid < 128){
    const float* w0 = (br ? bw0 : aw0) + tid*5;
    float g  = (br ? bg0 : ag0)[tid];
    float be = (br ? bbe0: abe0)[tid];
    float w[5], m5[5];
    #pragma unroll
    for (int i=0;i<5;++i){ w[i]=w0[i]; m5[i]=mom[i]*invM; }
    float mu = 0;
    #pragma unroll
    for (int i=0;i<5;++i) mu += w[i]*m5[i];
    const int I[15] = {0,0,0,0,0,1,1,1,1,2,2,2,3,3,4};
    const int J[15] = {0,1,2,3,4,1,2,3,4,2,3,4,3,4,4};
    float e2 = 0;
    #pragma unroll
    for (int t2=0;t2<15;++t2){
      float c = (I[t2]==J[t2]) ? 1.0f : 2.0f;
      e2 += c * w[I[t2]] * w[J[t2]] * (mom[5+t2]*invM);
    }
    float var = fmaxf(e2 - mu*mu, 0.0f);
    float A = g * rsqrtf(var + EPSV);
    #pragma unroll
    for (int i=0;i<5;++i) sF0[tid*5+i] = A*w[i];
    sFb0[tid] = be - A*mu;
  }
  if (PASS >= 2 && tid < 128){
    float s = y1s[br*128+tid]*invM, q = y1q[br*128+tid]*invM;
    float var = fmaxf(q - s*s, 0.0f);
    float g = (br ? bg1 : ag1)[tid], be = (br ? bbe1 : abe1)[tid];
    float A = g*rsqrtf(var + EPSV);
    sA1[tid] = A; sB1[tid] = be - A*s;
  }
  sStat[tid] = 0.0f; sStat[256+tid] = 0.0f;

  const int p = tid >> 1, h = tid & 1;
  const size_t gp = (size_t)blockIdx.x*128 + p;
  const float* nf = newf + gp*5;
  float x0 = nf[0], x1v = nf[1], x2v = nf[2], x3v = nf[3], x4v = nf[4];
  __syncthreads();
  #pragma unroll
  for (int cc = 0; cc < 8; ++cc){
    int oc = h*64 + cc*8;
    u32x4 vv;
    #pragma unroll
    for (int jj = 0; jj < 4; ++jj){
      int o = oc + jj*2;
      float ya = sFb0[o]   + sF0[o*5+0]*x0 + sF0[o*5+1]*x1v + sF0[o*5+2]*x2v + sF0[o*5+3]*x3v + sF0[o*5+4]*x4v;
      float yb = sFb0[o+1] + sF0[(o+1)*5+0]*x0 + sF0[(o+1)*5+1]*x1v + sF0[(o+1)*5+2]*x2v + sF0[(o+1)*5+3]*x3v + sF0[(o+1)*5+4]*x4v;
      vv[jj] = (unsigned)f2b(fmaxf(ya,0.0f)) | ((unsigned)f2b(fmaxf(yb,0.0f)) << 16);
    }
    *(u32x4*)((char*)sX + swz((unsigned)(p*256 + oc*2))) = vv;
  }
  __syncthreads();

  const int wv = tid >> 6, lane = tid & 63;
  const int mb = wv >> 1, nb = wv & 1;
  const int lrow = lane & 15, lk = lane >> 4;
  const unsigned short* w1g = w1b + br*16384;
  f32x4 zf = {0.0f, 0.0f, 0.0f, 0.0f};
  f32x4 acc[4][4];
  #pragma unroll
  for (int i=0;i<4;++i)
    #pragma unroll
    for (int j=0;j<4;++j) acc[i][j] = zf;

  #pragma unroll
  for (int ks = 0; ks < 4; ++ks){
    bf16x8 af[4], bfr[4];
    #pragma unroll
    for (int mf = 0; mf < 4; ++mf){
      int row = mb*64 + mf*16 + lrow;
      af[mf] = *(bf16x8*)((char*)sX + swz((unsigned)(row*256 + ks*64 + lk*16)));
    }
    #pragma unroll
    for (int nf2 = 0; nf2 < 4; ++nf2){
      int otile = nb*4 + nf2;
      bfr[nf2] = *(const bf16x8*)(w1g + ((otile*4 + ks)*64 + lane)*8);
    }
    #pragma unroll
    for (int mf = 0; mf < 4; ++mf)
      #pragma unroll
      for (int nf2 = 0; nf2 < 4; ++nf2)
        acc[mf][nf2] = __builtin_amdgcn_mfma_f32_16x16x32_bf16(af[mf], bfr[nf2], acc[mf][nf2], 0, 0, 0);
  }

  if (PASS == 1){
    #pragma unroll
    for (int nf2 = 0; nf2 < 4; ++nf2){
      float s = 0, q = 0;
      #pragma unroll
      for (int mf=0;mf<4;++mf)
        #pragma unroll
        for (int r=0;r<4;++r){ float v2 = acc[mf][nf2][r]; s += v2; q += v2*v2; }
      s += __shfl_xor(s,16); s += __shfl_xor(s,32);
      q += __shfl_xor(q,16); q += __shfl_xor(q,32);
      if (lane < 16){
        int o = nb*64 + nf2*16 + lrow;
        atomicAdd(&sStat[o], s);
        atomicAdd(&sStat[256+o], q);
      }
    }
    __syncthreads();
    if (tid < 128){
      atomicAdd(&y1s[br*128 + tid], sStat[tid]);
      atomicAdd(&y1q[br*128 + tid], sStat[256+tid]);
    }
    return;
  }

  __syncthreads();   // all waves done reading sX(x1)
  #pragma unroll
  for (int nf2 = 0; nf2 < 4; ++nf2){
    int o = nb*64 + nf2*16 + lrow;
    float A = sA1[o], Bc = sB1[o];
    #pragma unroll
    for (int mf = 0; mf < 4; ++mf)
      #pragma unroll
      for (int r = 0; r < 4; ++r){
        float xv = fmaxf(fmaf(A, acc[mf][nf2][r], Bc), 0.0f);
        int mm = mb*64 + mf*16 + lk*4 + r;
        *(unsigned short*)((char*)sX + swz((unsigned)(mm*256 + o*2))) = f2b(xv);
      }
  }
  __syncthreads();

  // L2 stat GEMM in FOUR 32-channel chunks (a2[4][2] keeps reg demand low)
  const unsigned short* w2 = w2b + br*32768;
  #pragma unroll
  for (int nh = 0; nh < 4; ++nh){
    f32x4 a2[4][2];
    #pragma unroll
    for (int i=0;i<4;++i)
      #pragma unroll
      for (int j=0;j<2;++j) a2[i][j] = zf;
    #pragma unroll
    for (int ks = 0; ks < 4; ++ks){
      bf16x8 af[4];
      #pragma unroll
      for (int mf = 0; mf < 4; ++mf){
        int row = mb*64 + mf*16 + lrow;
        af[mf] = *(bf16x8*)((char*)sX + swz((unsigned)(row*256 + ks*64 + lk*16)));
      }
      bf16x8 bw2f[2];
      #pragma unroll
      for (int nf2 = 0; nf2 < 2; ++nf2){
        int otile = nb*8 + nh*2 + nf2;
        bw2f[nf2] = *(const bf16x8*)(w2 + ((otile*4 + ks)*64 + lane)*8);
      }
      #pragma unroll
      for (int mf = 0; mf < 4; ++mf)
        #pragma unroll
        for (int nf2 = 0; nf2 < 2; ++nf2)
          a2[mf][nf2] = __builtin_amdgcn_mfma_f32_16x16x32_bf16(af[mf], bw2f[nf2], a2[mf][nf2], 0, 0, 0);
    }
    #pragma unroll
    for (int nf2 = 0; nf2 < 2; ++nf2){
      float s = 0, q = 0;
      #pragma unroll
      for (int mf=0;mf<4;++mf)
        #pragma unroll
        for (int r=0;r<4;++r){ float v2 = a2[mf][nf2][r]; s += v2; q += v2*v2; }
      s += __shfl_xor(s,16); s += __shfl_xor(s,32);
      q += __shfl_xor(q,16); q += __shfl_xor(q,32);
      if (lane < 16){
        int o = nb*128 + nh*32 + nf2*16 + lrow;
        atomicAdd(&sStat[o], s);
        atomicAdd(&sStat[256+o], q);
      }
    }
  }
  __syncthreads();
  atomicAdd(&y2s[br*256 + tid], sStat[tid]);
  atomicAdd(&y2q[br*256 + tid], sStat[256+tid]);
}

// ---------------- final pass: split-bf16, 256-thread blocks, BM=64 ----------
// launch_bounds(256,3): verified optimum (R9/R11/R13). Packed-weight loads.
__global__ __launch_bounds__(256,3) void k_pass3(
    const float* __restrict__ newf,
    const float* __restrict__ aw0, const float* __restrict__ bw0,
    const float* __restrict__ ag0, const float* __restrict__ bg0,
    const float* __restrict__ abe0, const float* __restrict__ bbe0,
    const float* __restrict__ ag1, const float* __restrict__ bg1,
    const float* __restrict__ abe1, const float* __restrict__ bbe1,
    const float* __restrict__ ag2, const float* __restrict__ bg2,
    const float* __restrict__ abe2, const float* __restrict__ bbe2,
    const unsigned short* __restrict__ w1h, const unsigned short* __restrict__ w1l,
    const unsigned short* __restrict__ w2h, const unsigned short* __restrict__ w2l,
    const float* __restrict__ mom,
    const float* __restrict__ y1s, const float* __restrict__ y1q,
    const float* __restrict__ y2s, const float* __restrict__ y2q,
    float* __restrict__ tout)
{
  __shared__ unsigned short sXh[64*128], sXl[64*128];
  __shared__ float sF0[128*5], sFb0[128];
  __shared__ float sA1[128], sB1[128];
  __shared__ float sA2[256], sB2[256];
  __shared__ float sT[4][64];

  const int tid = threadIdx.x;
  const int br = blockIdx.y;
  const float invM = 1.0f / (float)MPOS;

  if (tid < 128){
    const float* w0 = (br ? bw0 : aw0) + tid*5;
    float g  = (br ? bg0 : ag0)[tid];
    float be = (br ? bbe0: abe0)[tid];
    float w[5], m5[5];
    #pragma unroll
    for (int i=0;i<5;++i){ w[i]=w0[i]; m5[i]=mom[i]*invM; }
    float mu = 0;
    #pragma unroll
    for (int i=0;i<5;++i) mu += w[i]*m5[i];
    const int I[15] = {0,0,0,0,0,1,1,1,1,2,2,2,3,3,4};
    const int J[15] = {0,1,2,3,4,1,2,3,4,2,3,4,3,4,4};
    float e2 = 0;
    #pragma unroll
    for (int t2=0;t2<15;++t2){
      float c = (I[t2]==J[t2]) ? 1.0f : 2.0f;
      e2 += c * w[I[t2]] * w[J[t2]] * (mom[5+t2]*invM);
    }
    float var = fmaxf(e2 - mu*mu, 0.0f);
    float A = g * rsqrtf(var + EPSV);
    #pragma unroll
    for (int i=0;i<5;++i) sF0[tid*5+i] = A*w[i];
    sFb0[tid] = be - A*mu;

    float s1 = y1s[br*128+tid]*invM, q1 = y1q[br*128+tid]*invM;
    float var1 = fmaxf(q1 - s1*s1, 0.0f);
    float g1 = (br ? bg1 : ag1)[tid], be1 = (br ? bbe1 : abe1)[tid];
    float A1 = g1*rsqrtf(var1 + EPSV);
    sA1[tid] = A1; sB1[tid] = be1 - A1*s1;
  }
  {
    int c2 = tid;           // 256 threads cover 256 channels
    float s = y2s[br*256+c2]*invM, q = y2q[br*256+c2]*invM;
    float var = fmaxf(q - s*s, 0.0f);
    float g = (br ? bg2 : ag2)[c2], be = (br ? bbe2 : abe2)[c2];
    float A = g*rsqrtf(var + EPSV);
    sA2[c2] = A; sB2[c2] = be - A*s;
  }

  // x1 tile: 4 threads per position, 32 channels each; split hi/lo
  const int p = tid >> 2, h = tid & 3;
  const size_t gp = (size_t)blockIdx.x*64 + p;
  const float* nf = newf + gp*5;
  float x0 = nf[0], x1v = nf[1], x2v = nf[2], x3v = nf[3], x4v = nf[4];
  __syncthreads();
  #pragma unroll
  for (int cc = 0; cc < 4; ++cc){
    int oc = h*32 + cc*8;
    u32x4 vh, vl;
    #pragma unroll
    for (int jj = 0; jj < 4; ++jj){
      int o = oc + jj*2;
      float ya = sFb0[o]   + sF0[o*5+0]*x0 + sF0[o*5+1]*x1v + sF0[o*5+2]*x2v + sF0[o*5+3]*x3v + sF0[o*5+4]*x4v;
      float yb = sFb0[o+1] + sF0[(o+1)*5+0]*x0 + sF0[(o+1)*5+1]*x1v + sF0[(o+1)*5+2]*x2v + sF0[(o+1)*5+3]*x3v + sF0[(o+1)*5+4]*x4v;
      ya = fmaxf(ya, 0.0f); yb = fmaxf(yb, 0.0f);
      unsigned short ha = f2b(ya), hb = f2b(yb);
      unsigned short la = f2b(ya - b2f(ha)), lb = f2b(yb - b2f(hb));
      vh[jj] = (unsigned)ha | ((unsigned)hb << 16);
      vl[jj] = (unsigned)la | ((unsigned)lb << 16);
    }
    unsigned off = swz((unsigned)(p*256 + oc*2));
    *(u32x4*)((char*)sXh + off) = vh;
    *(u32x4*)((char*)sXl + off) = vl;
  }
  __syncthreads();

  // L1: y1[64x128] = x1 * W1^T; wave w owns 32 channels, all 64 rows (mf4)
  const int wv = tid >> 6, lane = tid & 63;
  const int lrow = lane & 15, lk = lane >> 4;
  const unsigned short* w1hb = w1h + br*16384;
  const unsigned short* w1lb = w1l + br*16384;
  f32x4 zf = {0.0f, 0.0f, 0.0f, 0.0f};
  f32x4 acc[4][2];
  #pragma unroll
  for (int i=0;i<4;++i)
    #pragma unroll
    for (int j=0;j<2;++j) acc[i][j] = zf;

  #pragma unroll
  for (int ks = 0; ks < 4; ++ks){
    bf16x8 ah[4], al[4], bh[2], bl[2];
    #pragma unroll
    for (int mf = 0; mf < 4; ++mf){
      unsigned off = swz((unsigned)((mf*16 + lrow)*256 + ks*64 + lk*16));
      ah[mf] = *(bf16x8*)((char*)sXh + off);
      al[mf] = *(bf16x8*)((char*)sXl + off);
    }
    #pragma unroll
    for (int nf2 = 0; nf2 < 2; ++nf2){
      int otile = wv*2 + nf2;
      bh[nf2] = *(const bf16x8*)(w1hb + ((otile*4 + ks)*64 + lane)*8);
      bl[nf2] = *(const bf16x8*)(w1lb + ((otile*4 + ks)*64 + lane)*8);
    }
    #pragma unroll
    for (int mf = 0; mf < 4; ++mf)
      #pragma unroll
      for (int nf2 = 0; nf2 < 2; ++nf2){
        acc[mf][nf2] = __builtin_amdgcn_mfma_f32_16x16x32_bf16(ah[mf], bh[nf2], acc[mf][nf2], 0, 0, 0);
        acc[mf][nf2] = __builtin_amdgcn_mfma_f32_16x16x32_bf16(ah[mf], bl[nf2], acc[mf][nf2], 0, 0, 0);
        acc[mf][nf2] = __builtin_amdgcn_mfma_f32_16x16x32_bf16(al[mf], bh[nf2], acc[mf][nf2], 0, 0, 0);
      }
  }

  __syncthreads();   // all waves done reading x1 tiles
  // x2 = relu(bn1(y1)) -> sXh/sXl (C/D: col=lane&15, row=(lane>>4)*4+r)
  #pragma unroll
  for (int nf2 = 0; nf2 < 2; ++nf2){
    int o = wv*32 + nf2*16 + lrow;
    float A = sA1[o], Bc = sB1[o];
    #pragma unroll
    for (int mf = 0; mf < 4; ++mf)
      #pragma unroll
      for (int r = 0; r < 4; ++r){
        float xv = fmaxf(fmaf(A, acc[mf][nf2][r], Bc), 0.0f);
        int mm = mf*16 + lk*4 + r;
        unsigned short hi = f2b(xv);
        unsigned short lo = f2b(xv - b2f(hi));
        unsigned off = swz((unsigned)(mm*256 + o*2));
        *(unsigned short*)((char*)sXh + off) = hi;
        *(unsigned short*)((char*)sXl + off) = lo;
      }
  }
  __syncthreads();

  // L2: y2[64x256] = x2 * W2^T; wave w owns channels w*64..w*64+63 (2 chunks)
  const unsigned short* w2hb = w2h + br*32768;
  const unsigned short* w2lb = w2l + br*32768;
  float mxv[4][4];
  #pragma unroll
  for (int mf=0;mf<4;++mf)
    #pragma unroll
    for (int r=0;r<4;++r) mxv[mf][r] = 0.0f;   // relu >= 0

  #pragma unroll
  for (int nh = 0; nh < 2; ++nh){
    f32x4 a2[4][2];
    #pragma unroll
    for (int i=0;i<4;++i)
      #pragma unroll
      for (int j=0;j<2;++j) a2[i][j] = zf;
    #pragma unroll
    for (int ks = 0; ks < 4; ++ks){
      bf16x8 ah[4], al[4], bh[2], bl[2];
      #pragma unroll
      for (int mf = 0; mf < 4; ++mf){
        unsigned off = swz((unsigned)((mf*16 + lrow)*256 + ks*64 + lk*16));
        ah[mf] = *(bf16x8*)((char*)sXh + off);
        al[mf] = *(bf16x8*)((char*)sXl + off);
      }
      #pragma unroll
      for (int nf2 = 0; nf2 < 2; ++nf2){
        int otile = wv*4 + nh*2 + nf2;
        bh[nf2] = *(const bf16x8*)(w2hb + ((otile*4 + ks)*64 + lane)*8);
        bl[nf2] = *(const bf16x8*)(w2lb + ((otile*4 + ks)*64 + lane)*8);
      }
      #pragma unroll
      for (int mf = 0; mf < 4; ++mf)
        #pragma unroll
        for (int nf2 = 0; nf2 < 2; ++nf2){
          a2[mf][nf2] = __builtin_amdgcn_mfma_f32_16x16x32_bf16(ah[mf], bh[nf2], a2[mf][nf2], 0, 0, 0);
          a2[mf][nf2] = __builtin_amdgcn_mfma_f32_16x16x32_bf16(ah[mf], bl[nf2], a2[mf][nf2], 0, 0, 0);
          a2[mf][nf2] = __builtin_amdgcn_mfma_f32_16x16x32_bf16(al[mf], bh[nf2], a2[mf][nf2], 0, 0, 0);
        }
    }
    // bn2 + relu + running channel-max for this chunk
    #pragma unroll
    for (int mf = 0; mf < 4; ++mf)
      #pragma unroll
      for (int r = 0; r < 4; ++r){
        #pragma unroll
        for (int nf2 = 0; nf2 < 2; ++nf2){
          int o = wv*64 + nh*32 + nf2*16 + lrow;
          mxv[mf][r] = fmaxf(mxv[mf][r], fmaxf(fmaf(sA2[o], a2[mf][nf2][r], sB2[o]), 0.0f));
        }
      }
  }

  // per-wave max over its 64 channels -> sT[w][row]
  #pragma unroll
  for (int mf = 0; mf < 4; ++mf)
    #pragma unroll
    for (int r = 0; r < 4; ++r){
      float mx = mxv[mf][r];
      mx = fmaxf(mx, __shfl_xor(mx,1));
      mx = fmaxf(mx, __shfl_xor(mx,2));
      mx = fmaxf(mx, __shfl_xor(mx,4));
      mx = fmaxf(mx, __shfl_xor(mx,8));
      if (lrow == 0) sT[wv][mf*16 + lk*4 + r] = mx;
    }
  __syncthreads();
  if (tid < 64){
    float t0 = fmaxf(sT[0][tid], sT[1][tid]);
    float t1 = fmaxf(sT[2][tid], sT[3][tid]);
    tout[(size_t)br*MPOS + (size_t)blockIdx.x*64 + tid] = fmaxf(t0, t1);
  }
}

// ---------------- softmax + weighted sums ----------------
__global__ void k_final(const float* __restrict__ tbuf, const int* __restrict__ nn_idx,
                        const float* __restrict__ gpx, const float* __restrict__ gpy,
                        const float* __restrict__ gpz,
                        const float* __restrict__ fT, float* __restrict__ out){
  __shared__ float sw[4][64];
  const int wv = threadIdx.x >> 6, lane = threadIdx.x & 63;
  const int m = blockIdx.x*4 + wv, b = blockIdx.y;
  const size_t pos0 = (size_t)(b*NQ + m)*KNN;
  const int half = lane >> 5, kk = lane & 31;
  float tv = tbuf[(size_t)half*MPOS + pos0 + kk];
  float mx = tv;
  #pragma unroll
  for (int s=1;s<32;s<<=1) mx = fmaxf(mx, __shfl_xor(mx, s));
  float e = __expf(tv - mx);
  float sum = e;
  #pragma unroll
  for (int s=1;s<32;s<<=1) sum += __shfl_xor(sum, s);
  sw[wv][lane] = e / sum;    // lanes 0..31: wts (a), 32..63: wts1 (b)
  __syncthreads();
  const int* nn = nn_idx + pos0;
  float ax=0, ay=0, az=0, f0=0, f1=0;
  for (int k=0;k<KNN;++k){
    int idx = nn[k];
    float wa = sw[wv][k], wb = sw[wv][32+k];
    ax = fmaf(wa, gpx[b*NPTS+idx], ax);
    ay = fmaf(wa, gpy[b*NPTS+idx], ay);
    az = fmaf(wa, gpz[b*NPTS+idx], az);
    float2 fv = *(const float2*)(fT + ((size_t)b*NPTS + idx)*CF + lane*2);
    f0 = fmaf(wb, fv.x, f0);
    f1 = fmaf(wb, fv.y, f1);
  }
  if (lane == 0){
    out[((size_t)b*131 + 0)*NQ + m] = ax;
    out[((size_t)b*131 + 1)*NQ + m] = ay;
    out[((size_t)b*131 + 2)*NQ + m] = az;
  }
  out[((size_t)b*131 + 3 + lane*2)*NQ + m] = f0;
  out[((size_t)b*131 + 4 + lane*2)*NQ + m] = f1;
}

extern "C" void kernel_launch(void* const* d_in, const int* in_sizes, int n_in,
                              void* d_out, int out_size, void* d_ws, size_t ws_size,
                              hipStream_t stream){
  const float* points1   = (const float*)d_in[0];
  const float* points2   = (const float*)d_in[1];
  const float* features1 = (const float*)d_in[2];
  const float* features2 = (const float*)d_in[3];
  const int*   randidx   = (const int*)d_in[4];
  const float* aw0 = (const float*)d_in[6];
  const float* ag0 = (const float*)d_in[8];
  const float* abe0= (const float*)d_in[9];
  const float* aw1 = (const float*)d_in[10];
  const float* ag1 = (const float*)d_in[12];
  const float* abe1= (const float*)d_in[13];
  const float* aw2 = (const float*)d_in[14];
  const float* ag2 = (const float*)d_in[16];
  const float* abe2= (const float*)d_in[17];
  const float* bw0 = (const float*)d_in[18];
  const float* bg0 = (const float*)d_in[20];
  const float* bbe0= (const float*)d_in[21];
  const float* bw1 = (const float*)d_in[22];
  const float* bg1 = (const float*)d_in[24];
  const float* bbe1= (const float*)d_in[25];
  const float* bw2 = (const float*)d_in[26];
  const float* bg2 = (const float*)d_in[28];
  const float* bbe2= (const float*)d_in[29];

  char* ws = (char*)d_ws;
  float* px   = (float*)(ws + 0);
  float* py   = (float*)(ws + 65536);
  float* pz   = (float*)(ws + 131072);
  float* fT   = (float*)(ws + 196608);                    // 8MB f32 [b][p][c]
  unsigned short* w1h = (unsigned short*)(ws + 8585216);  // 64KB (packed)
  unsigned short* w2h = (unsigned short*)(ws + 8650752);  // 128KB (packed)
  unsigned short* w1l = (unsigned short*)(ws + 8781824);  // 64KB (packed)
  unsigned short* w2l = (unsigned short*)(ws + 8847360);  // 128KB (packed)
  int*   nn   = (int*)(ws + 8978432);                     // 1MB
  float* newf = (float*)(ws + 10027008);                  // 5.24MB [pos][5]
  float* tbuf = (float*)(ws + 15269888);                  // 2MB [branch][pos]
  float* mom  = (float*)(ws + 17367040);                  // stats block
  float* y1s = mom + 20;  float* y1q = y1s + 256;
  float* y2s = y1q + 256; float* y2q = y2s + 512;

  hipMemsetAsync(mom, 0, 6224, stream);
  k_prep<<<dim3(448), 256, 0, stream>>>(points1, points2, aw1, bw1, aw2, bw2,
      px, py, pz, w1h, w1l, w2h, w2l);
  k_transpose_f<<<dim3(256,4,2), 256, 0, stream>>>(features1, features2, fT);
  k_knn<<<dim3(256,2), 1024, 0, stream>>>(px, py, pz, randidx, fT, nn, newf, mom);
  k_pass<1><<<dim3(2048,2), 256, 0, stream>>>(newf, aw0,bw0, ag0,bg0, abe0,bbe0,
      ag1,bg1, abe1,bbe1, w1h,w2h, mom, y1s,y1q,y2s,y2q);
  k_pass<2><<<dim3(2048,2), 256, 0, stream>>>(newf, aw0,bw0, ag0,bg0, abe0,bbe0,
      ag1,bg1, abe1,bbe1, w1h,w2h, mom, y1s,y1q,y2s,y2q);
  k_pass3<<<dim3(4096,2), 256, 0, stream>>>(newf, aw0,bw0, ag0,bg0, abe0,bbe0,
      ag1,bg1, abe1,bbe1, ag2,bg2, abe2,bbe2, w1h,w1l,w2h,w2l, mom,
      y1s,y1q,y2s,y2q, tbuf);
  k_final<<<dim3(1024,2), 256, 0, stream>>>(tbuf, nn, px, py, pz, fT, (float*)d_out);
}